// Round 1
// baseline (2395.156 us; speedup 1.0000x reference)
//
#include <hip/hip_runtime.h>
#include <math.h>

typedef unsigned int u32;

// ---------- bf16 helpers (manual bit ops, RNE) ----------
__device__ inline u32 bf16r(float x){
  u32 u = __float_as_uint(x);
  return (u + 0x7fffu + ((u >> 16) & 1u)) >> 16;
}
__device__ inline u32 pack2(float a, float b){ return bf16r(a) | (bf16r(b) << 16); }
__device__ inline uint4 pack8(const float* f){
  uint4 v; v.x = pack2(f[0],f[1]); v.y = pack2(f[2],f[3]);
  v.z = pack2(f[4],f[5]); v.w = pack2(f[6],f[7]); return v;
}
__device__ inline void unpack8(uint4 v, float* f){
  f[0]=__uint_as_float(v.x<<16); f[1]=__uint_as_float(v.x&0xffff0000u);
  f[2]=__uint_as_float(v.y<<16); f[3]=__uint_as_float(v.y&0xffff0000u);
  f[4]=__uint_as_float(v.z<<16); f[5]=__uint_as_float(v.z&0xffff0000u);
  f[6]=__uint_as_float(v.w<<16); f[7]=__uint_as_float(v.w&0xffff0000u);
}

// ---------- f32 -> bf16 weight conversion (8 elems/thread) ----------
__global__ void k_cvt(const float* __restrict__ in, uint4* __restrict__ out, int n8){
  int i = blockIdx.x*256 + threadIdx.x;
  if (i >= n8) return;
  const float4* in4 = (const float4*)in;
  float4 a = in4[(size_t)i*2], b = in4[(size_t)i*2+1];
  float f[8] = {a.x,a.y,a.z,a.w,b.x,b.y,b.z,b.w};
  out[i] = pack8(f);
}

// ---------- per-edge scalars + CSR in-edge lists ----------
__global__ void k_pre(const int* __restrict__ ei, const int* __restrict__ n2g,
                      const int* __restrict__ nl, const float* __restrict__ sigmas,
                      const float* __restrict__ pos, const float* __restrict__ dn, int E,
                      float* __restrict__ pd, int* __restrict__ cnt, int* __restrict__ inlist){
  int e = blockIdx.x*256 + threadIdx.x;
  if (e >= E) return;
  int r = ei[e], c = ei[E+e];
  float sg = sigmas[nl[n2g[r]]];
  float dx = pos[3*r]-pos[3*c], dy = pos[3*r+1]-pos[3*c+1], dz = pos[3*r+2]-pos[3*c+2];
  float d = sqrtf(dx*dx + dy*dy + dz*dz);
  pd[e] = d + dn[e]*sg;
  int slot = atomicAdd(&cnt[c], 1);
  if (slot < 8) inlist[c*8 + slot] = e;
}

// ---------- x = node_emb[atom_type] ----------
__global__ void k_ninit(const int* __restrict__ at, const float* __restrict__ nemb,
                        float* __restrict__ x, int N){
  int idx = blockIdx.x*256 + threadIdx.x;     // over N*64 float4 chunks
  int i = idx >> 6, c = idx & 63;
  if (i >= N) return;
  ((float4*)x)[(size_t)i*64 + c] = ((const float4*)nemb)[(size_t)at[i]*64 + c];
}

// ---------- edge_attr = (relu(pd*W1+b1) @ W2 + b2) * edge_emb[type]  [bf16 out] ----------
// BM=64 edges/block, 256 thr: 32 col-groups x 8 row-groups, acc[8 rows][8 cols]
__global__ __launch_bounds__(256) void k_attr(
    const float* __restrict__ pd, const float* __restrict__ W1, const float* __restrict__ b1,
    const uint4* __restrict__ W2bf, const float* __restrict__ b2,
    const int* __restrict__ etype, const float* __restrict__ eemb,
    uint4* __restrict__ attr, int E)
{
  __shared__ uint4 Als[64*32];   // hidden tile [64][256] bf16
  __shared__ uint4 Wls[8*32];    // W slice [8][256] bf16
  int tid = threadIdx.x;
  int base = blockIdx.x*64;
  // stage hidden = relu(pd*W1+b1)
  for (int q=0;q<8;q++){
    int lin = q*256 + tid;
    int el = lin >> 5, h8 = (lin & 31)*8;
    int e = base + el;
    float f[8];
    if (e < E){
      float p = pd[e];
      float4 wa = *(const float4*)(W1+h8), wb = *(const float4*)(W1+h8+4);
      float4 ba = *(const float4*)(b1+h8), bb = *(const float4*)(b1+h8+4);
      f[0]=fmaxf(p*wa.x+ba.x,0.f); f[1]=fmaxf(p*wa.y+ba.y,0.f);
      f[2]=fmaxf(p*wa.z+ba.z,0.f); f[3]=fmaxf(p*wa.w+ba.w,0.f);
      f[4]=fmaxf(p*wb.x+bb.x,0.f); f[5]=fmaxf(p*wb.y+bb.y,0.f);
      f[6]=fmaxf(p*wb.z+bb.z,0.f); f[7]=fmaxf(p*wb.w+bb.w,0.f);
    } else { for (int t=0;t<8;t++) f[t]=0.f; }
    Als[lin] = pack8(f);
  }
  __syncthreads();
  int cg = tid & 31, rg = tid >> 5, n0 = cg*8;
  float acc[8][8];
  #pragma unroll
  for (int i=0;i<8;i++) for (int c=0;c<8;c++) acc[i][c]=0.f;
  for (int kk=0; kk<256; kk+=8){
    __syncthreads();
    { int j = tid >> 5, c8 = tid & 31; Wls[tid] = W2bf[(size_t)(kk+j)*32 + c8]; }
    __syncthreads();
    float wf[8][8];
    #pragma unroll
    for (int j=0;j<8;j++) unpack8(Wls[j*32 + cg], wf[j]);
    #pragma unroll
    for (int i=0;i<8;i++){
      float af[8];
      unpack8(Als[(rg*8+i)*32 + (kk>>3)], af);
      #pragma unroll
      for (int j=0;j<8;j++)
        #pragma unroll
        for (int c=0;c<8;c++) acc[i][c] += af[j]*wf[j][c];
    }
  }
  float bv[8];
  #pragma unroll
  for (int c=0;c<8;c++) bv[c] = b2[n0+c];
  for (int i=0;i<8;i++){
    int e = base + rg*8 + i;
    if (e < E){
      const float* ee = eemb + (size_t)etype[e]*256 + n0;
      float f[8];
      #pragma unroll
      for (int c=0;c<8;c++) f[c] = (acc[i][c] + bv[c]) * ee[c];
      attr[((size_t)e*256 + n0) >> 3] = pack8(f);
    }
  }
}

// ---------- hin[j] = x[j] + sum_in relu(x[row]+attr)  (gather via CSR) ----------
__global__ void k_agg(const float* __restrict__ x, const uint2* __restrict__ attr2,
                      const int* __restrict__ ei, const int* __restrict__ cnt,
                      const int* __restrict__ inlist, float* __restrict__ hin, int N){
  int tid = threadIdx.x;
  int j = blockIdx.x*4 + (tid >> 6);
  int lane = tid & 63;
  if (j >= N) return;
  const float4* x4 = (const float4*)x;
  float4 a = x4[(size_t)j*64 + lane];
  int deg = min(cnt[j], 8);
  for (int s=0; s<deg; s++){
    int e = inlist[j*8 + s];
    int r = ei[e];
    float4 xr = x4[(size_t)r*64 + lane];
    uint2 av = attr2[(size_t)e*64 + lane];
    a.x += fmaxf(xr.x + __uint_as_float(av.x<<16), 0.f);
    a.y += fmaxf(xr.y + __uint_as_float(av.x&0xffff0000u), 0.f);
    a.z += fmaxf(xr.z + __uint_as_float(av.y<<16), 0.f);
    a.w += fmaxf(xr.w + __uint_as_float(av.y&0xffff0000u), 0.f);
  }
  ((float4*)hin)[(size_t)j*64 + lane] = a;
}

// ---------- fused GIN MLP: x += (maybe-relu)(relu(hin@W1+b1)@W2+b2) ----------
// BM=32 rows, 256 thr: 32 cg x 8 rg x 4 rows, acc[4][8]
__global__ __launch_bounds__(256) void k_mlp(
    const float* __restrict__ hin, const uint4* __restrict__ W1bf, const float* __restrict__ b1,
    const uint4* __restrict__ W2bf, const float* __restrict__ b2,
    float* __restrict__ x, int N, int do_relu)
{
  __shared__ uint4 Als[32*32];
  __shared__ uint4 T1 [32*32];
  __shared__ uint4 Wls[8*32];
  int tid = threadIdx.x;
  int base = blockIdx.x*32;
  for (int q=0;q<4;q++){
    int lin = q*256 + tid;
    int el = lin >> 5, h8 = (lin & 31)*8;
    int r = base + el;
    float f[8];
    if (r < N){
      const float4* p = (const float4*)(hin + (size_t)r*256 + h8);
      float4 a = p[0], b = p[1];
      f[0]=a.x; f[1]=a.y; f[2]=a.z; f[3]=a.w; f[4]=b.x; f[5]=b.y; f[6]=b.z; f[7]=b.w;
    } else { for (int t=0;t<8;t++) f[t]=0.f; }
    Als[lin] = pack8(f);
  }
  __syncthreads();
  int cg = tid & 31, rg = tid >> 5, n0 = cg*8;
  float acc[4][8];
  #pragma unroll
  for (int i=0;i<4;i++) for (int c=0;c<8;c++) acc[i][c]=0.f;
  for (int kk=0; kk<256; kk+=8){
    __syncthreads();
    { int j = tid >> 5, c8 = tid & 31; Wls[tid] = W1bf[(size_t)(kk+j)*32 + c8]; }
    __syncthreads();
    float wf[8][8];
    #pragma unroll
    for (int j=0;j<8;j++) unpack8(Wls[j*32 + cg], wf[j]);
    #pragma unroll
    for (int i=0;i<4;i++){
      float af[8];
      unpack8(Als[(rg*4+i)*32 + (kk>>3)], af);
      #pragma unroll
      for (int j=0;j<8;j++)
        #pragma unroll
        for (int c=0;c<8;c++) acc[i][c] += af[j]*wf[j][c];
    }
  }
  {
    float bv[8];
    #pragma unroll
    for (int c=0;c<8;c++) bv[c] = b1[n0+c];
    for (int i=0;i<4;i++){
      float f[8];
      #pragma unroll
      for (int c=0;c<8;c++) f[c] = fmaxf(acc[i][c] + bv[c], 0.f);
      T1[(rg*4+i)*32 + cg] = pack8(f);
    }
  }
  float acc2[4][8];
  #pragma unroll
  for (int i=0;i<4;i++) for (int c=0;c<8;c++) acc2[i][c]=0.f;
  for (int kk=0; kk<256; kk+=8){
    __syncthreads();
    { int j = tid >> 5, c8 = tid & 31; Wls[tid] = W2bf[(size_t)(kk+j)*32 + c8]; }
    __syncthreads();
    float wf[8][8];
    #pragma unroll
    for (int j=0;j<8;j++) unpack8(Wls[j*32 + cg], wf[j]);
    #pragma unroll
    for (int i=0;i<4;i++){
      float af[8];
      unpack8(T1[(rg*4+i)*32 + (kk>>3)], af);
      #pragma unroll
      for (int j=0;j<8;j++)
        #pragma unroll
        for (int c=0;c<8;c++) acc2[i][c] += af[j]*wf[j][c];
    }
  }
  float bv[8];
  #pragma unroll
  for (int c=0;c<8;c++) bv[c] = b2[n0+c];
  for (int i=0;i<4;i++){
    int r = base + rg*4 + i;
    if (r < N){
      float* px = x + (size_t)r*256 + n0;
      float4 x0 = *(float4*)px, x1 = *(float4*)(px+4);
      float h[8];
      #pragma unroll
      for (int c=0;c<8;c++){
        h[c] = acc2[i][c] + bv[c];
        if (do_relu) h[c] = fmaxf(h[c], 0.f);
      }
      x0.x += h[0]; x0.y += h[1]; x0.z += h[2]; x0.w += h[3];
      x1.x += h[4]; x1.y += h[5]; x1.z += h[6]; x1.w += h[7];
      *(float4*)px = x0; *(float4*)(px+4) = x1;
    }
  }
}

// ---------- fused head: feat=[x_r*x_c, attr]; 3 layers; loss = 0.5*(s+dn)^2 -> atomic out[g] ----------
// BM=32 edges
__global__ __launch_bounds__(256) void k_head(
    const float* __restrict__ x, const uint4* __restrict__ attr4,
    const int* __restrict__ ei, const int* __restrict__ n2g,
    const uint4* __restrict__ W1bf, const float* __restrict__ ob1,
    const uint4* __restrict__ W2bf, const float* __restrict__ ob2,
    const float* __restrict__ W3, const float* __restrict__ ob3,
    const float* __restrict__ dnoise, float* __restrict__ out, int E)
{
  __shared__ uint4 F [32*64];   // feat [32][512] bf16
  __shared__ uint4 T1[32*32];   // [32][256] bf16
  __shared__ uint4 T2[32*16];   // [32][128] bf16
  __shared__ uint4 Wls[8*32];
  __shared__ float W3s[128];
  int tid = threadIdx.x;
  int base = blockIdx.x*32;
  for (int q=0;q<8;q++){
    int lin = q*256 + tid;
    int el = lin >> 6, h8 = (lin & 63)*8;
    int e = base + el;
    uint4 v;
    if (e < E){
      if (h8 < 256){
        int r = ei[e], c = ei[E+e];
        const float4* xr = (const float4*)(x + (size_t)r*256 + h8);
        const float4* xc = (const float4*)(x + (size_t)c*256 + h8);
        float4 a0 = xr[0], a1 = xr[1], b0 = xc[0], b1 = xc[1];
        float f[8] = {a0.x*b0.x, a0.y*b0.y, a0.z*b0.z, a0.w*b0.w,
                      a1.x*b1.x, a1.y*b1.y, a1.z*b1.z, a1.w*b1.w};
        v = pack8(f);
      } else {
        v = attr4[((size_t)e*256 + (h8-256)) >> 3];
      }
    } else v = make_uint4(0,0,0,0);
    F[lin] = v;
  }
  if (tid < 128) W3s[tid] = W3[tid];
  __syncthreads();
  // L1: K=512 N=256
  int cg = tid & 31, rg = tid >> 5, n0 = cg*8;
  float acc[4][8];
  #pragma unroll
  for (int i=0;i<4;i++) for (int c=0;c<8;c++) acc[i][c]=0.f;
  for (int kk=0; kk<512; kk+=8){
    __syncthreads();
    { int j = tid >> 5, c8 = tid & 31; Wls[tid] = W1bf[(size_t)(kk+j)*32 + c8]; }
    __syncthreads();
    float wf[8][8];
    #pragma unroll
    for (int j=0;j<8;j++) unpack8(Wls[j*32 + cg], wf[j]);
    #pragma unroll
    for (int i=0;i<4;i++){
      float af[8];
      unpack8(F[(rg*4+i)*64 + (kk>>3)], af);
      #pragma unroll
      for (int j=0;j<8;j++)
        #pragma unroll
        for (int c=0;c<8;c++) acc[i][c] += af[j]*wf[j][c];
    }
  }
  {
    float bv[8];
    #pragma unroll
    for (int c=0;c<8;c++) bv[c] = ob1[n0+c];
    for (int i=0;i<4;i++){
      float f[8];
      #pragma unroll
      for (int c=0;c<8;c++) f[c] = fmaxf(acc[i][c] + bv[c], 0.f);
      T1[(rg*4+i)*32 + cg] = pack8(f);
    }
  }
  // L2: K=256 N=128 ; 16 cg x 16 rg x 2 rows
  int cg2 = tid & 15, rg2 = tid >> 4, m0 = cg2*8;
  float acc2[2][8];
  #pragma unroll
  for (int i=0;i<2;i++) for (int c=0;c<8;c++) acc2[i][c]=0.f;
  for (int kk=0; kk<256; kk+=8){
    __syncthreads();
    if (tid < 128){ int j = tid >> 4, c8 = tid & 15; Wls[j*16 + c8] = W2bf[(size_t)(kk+j)*16 + c8]; }
    __syncthreads();
    float wf[8][8];
    #pragma unroll
    for (int j=0;j<8;j++) unpack8(Wls[j*16 + cg2], wf[j]);
    #pragma unroll
    for (int i=0;i<2;i++){
      float af[8];
      unpack8(T1[(rg2*2+i)*32 + (kk>>3)], af);
      #pragma unroll
      for (int j=0;j<8;j++)
        #pragma unroll
        for (int c=0;c<8;c++) acc2[i][c] += af[j]*wf[j][c];
    }
  }
  {
    float bv[8];
    #pragma unroll
    for (int c=0;c<8;c++) bv[c] = ob2[m0+c];
    for (int i=0;i<2;i++){
      float f[8];
      #pragma unroll
      for (int c=0;c<8;c++) f[c] = fmaxf(acc2[i][c] + bv[c], 0.f);
      T2[(rg2*2+i)*16 + cg2] = pack8(f);
    }
  }
  __syncthreads();
  // L3: K=128 N=1 + loss
  int el = tid >> 3, part = tid & 7;
  float s = 0.f;
  {
    uint4 v0 = T2[el*16 + part*2], v1 = T2[el*16 + part*2 + 1];
    float f0[8], f1[8];
    unpack8(v0, f0); unpack8(v1, f1);
    int c0 = part*16;
    #pragma unroll
    for (int c=0;c<8;c++){ s += f0[c]*W3s[c0+c]; s += f1[c]*W3s[c0+8+c]; }
  }
  s += __shfl_xor(s, 1);
  s += __shfl_xor(s, 2);
  s += __shfl_xor(s, 4);
  if (part == 0){
    int e = base + el;
    if (e < E){
      float sv = s + ob3[0];
      float dn = dnoise[e];
      float l = 0.5f*(sv + dn)*(sv + dn);
      atomicAdd(&out[n2g[ei[e]]], l);
    }
  }
}

// =========================== host ===========================
static inline size_t alignup(size_t v){ return (v + 255) & ~(size_t)255; }

extern "C" void kernel_launch(void* const* d_in, const int* in_sizes, int n_in,
                              void* d_out, int out_size, void* d_ws, size_t ws_size,
                              hipStream_t stream) {
  const int*   at    = (const int*)  d_in[0];
  const int*   ei    = (const int*)  d_in[1];
  const int*   etype = (const int*)  d_in[2];
  const int*   n2g   = (const int*)  d_in[3];
  const int*   nl    = (const int*)  d_in[4];
  const float* pos   = (const float*)d_in[5];
  const float* dnoi  = (const float*)d_in[6];
  const float* sig   = (const float*)d_in[7];
  const float* nemb  = (const float*)d_in[8];
  const float* eemb  = (const float*)d_in[9];
  const float* inW1  = (const float*)d_in[10];
  const float* inb1  = (const float*)d_in[11];
  const float* inW2  = (const float*)d_in[12];
  const float* inb2  = (const float*)d_in[13];
  const float* gW1   = (const float*)d_in[14];
  const float* gb1   = (const float*)d_in[15];
  const float* gW2   = (const float*)d_in[16];
  const float* gb2   = (const float*)d_in[17];
  const float* oW1   = (const float*)d_in[18];
  const float* ob1   = (const float*)d_in[19];
  const float* oW2   = (const float*)d_in[20];
  const float* ob2   = (const float*)d_in[21];
  const float* oW3   = (const float*)d_in[22];
  const float* ob3   = (const float*)d_in[23];
  float* out = (float*)d_out;

  const int N = in_sizes[0];
  const int E = in_sizes[2];
  const int G = in_sizes[4];
  const int H = 256;

  // workspace layout
  char* w = (char*)d_ws;
  size_t off = 0;
  size_t o_attr   = off; off = alignup(off + (size_t)E*H*2);      // bf16 edge_attr
  size_t o_x      = off; off = alignup(off + (size_t)N*H*4);      // f32 x
  size_t o_hin    = off; off = alignup(off + (size_t)N*H*4);      // f32 x+agg
  size_t o_pd     = off; off = alignup(off + (size_t)E*4);
  size_t o_cnt    = off; off = alignup(off + (size_t)N*4);
  size_t o_inl    = off; off = alignup(off + (size_t)N*8*4);
  size_t o_w2bf   = off; off = alignup(off + (size_t)H*H*2);      // in_W2 bf16
  size_t o_gw1bf  = off; off = alignup(off + (size_t)4*H*H*2);
  size_t o_gw2bf  = off; off = alignup(off + (size_t)4*H*H*2);
  size_t o_ow1bf  = off; off = alignup(off + (size_t)2*H*H*2);
  size_t o_ow2bf  = off; off = alignup(off + (size_t)H*(H/2)*2);
  (void)ws_size; (void)n_in; (void)out_size;

  uint4* attr4 = (uint4*)(w + o_attr);
  float* x     = (float*)(w + o_x);
  float* hin   = (float*)(w + o_hin);
  float* pd    = (float*)(w + o_pd);
  int*   cnt   = (int*)  (w + o_cnt);
  int*   inl   = (int*)  (w + o_inl);
  uint4* w2bf  = (uint4*)(w + o_w2bf);
  uint4* gw1bf = (uint4*)(w + o_gw1bf);
  uint4* gw2bf = (uint4*)(w + o_gw2bf);
  uint4* ow1bf = (uint4*)(w + o_ow1bf);
  uint4* ow2bf = (uint4*)(w + o_ow2bf);

  hipMemsetAsync(cnt, 0, (size_t)N*4, stream);
  hipMemsetAsync(out, 0, (size_t)G*4, stream);

  // weight conversions
  {
    int n8;
    n8 = H*H/8;       k_cvt<<<(n8+255)/256, 256, 0, stream>>>(inW2, w2bf, n8);
    n8 = 4*H*H/8;     k_cvt<<<(n8+255)/256, 256, 0, stream>>>(gW1, gw1bf, n8);
    n8 = 4*H*H/8;     k_cvt<<<(n8+255)/256, 256, 0, stream>>>(gW2, gw2bf, n8);
    n8 = 2*H*H/8;     k_cvt<<<(n8+255)/256, 256, 0, stream>>>(oW1, ow1bf, n8);
    n8 = H*(H/2)/8;   k_cvt<<<(n8+255)/256, 256, 0, stream>>>(oW2, ow2bf, n8);
  }

  k_pre<<<(E+255)/256, 256, 0, stream>>>(ei, n2g, nl, sig, pos, dnoi, E, pd, cnt, inl);
  k_ninit<<<(N*64+255)/256, 256, 0, stream>>>(at, nemb, x, N);
  k_attr<<<(E+63)/64, 256, 0, stream>>>(pd, inW1, inb1, w2bf, inb2, etype, eemb, attr4, E);

  for (int c=0; c<4; c++){
    k_agg<<<(N+3)/4, 256, 0, stream>>>(x, (const uint2*)attr4, ei, cnt, inl, hin, N);
    k_mlp<<<(N+31)/32, 256, 0, stream>>>(hin,
        gw1bf + (size_t)c*H*H/8, gb1 + (size_t)c*H,
        gw2bf + (size_t)c*H*H/8, gb2 + (size_t)c*H,
        x, N, (c<3) ? 1 : 0);
  }

  k_head<<<(E+31)/32, 256, 0, stream>>>(x, attr4, ei, n2g,
      ow1bf, ob1, ow2bf, ob2, oW3, ob3, dnoi, out, E);
}

// Round 2
// 1050.714 us; speedup vs baseline: 2.2796x; 2.2796x over previous
//
#include <hip/hip_runtime.h>
#include <math.h>

typedef unsigned int u32;
typedef __attribute__((ext_vector_type(8))) short bf16x8;
typedef __attribute__((ext_vector_type(4))) float f32x4;

#define MFMA16(a,b,c) __builtin_amdgcn_mfma_f32_16x16x32_bf16(a,b,c,0,0,0)

// ---------- bf16 helpers (manual bit ops, RNE) ----------
__device__ inline u32 bf16r(float x){
  u32 u = __float_as_uint(x);
  return (u + 0x7fffu + ((u >> 16) & 1u)) >> 16;
}
__device__ inline u32 pack2(float a, float b){ return bf16r(a) | (bf16r(b) << 16); }
__device__ inline uint4 pack8(const float* f){
  uint4 v; v.x = pack2(f[0],f[1]); v.y = pack2(f[2],f[3]);
  v.z = pack2(f[4],f[5]); v.w = pack2(f[6],f[7]); return v;
}
__device__ inline float bf2f(short s){ return __uint_as_float(((u32)(unsigned short)s) << 16); }

// ---------- f32 [K][Nf] -> bf16 transposed [Nf][K] ----------
__global__ void k_cvtT(const float* __restrict__ in, short* __restrict__ out, int K, int Nf){
  int tid = blockIdx.x*256 + threadIdx.x;
  int K8 = K >> 3;
  if (tid >= Nf*K8) return;
  int n = tid / K8, k8 = tid % K8;
  float f[8];
  #pragma unroll
  for (int j=0;j<8;j++) f[j] = in[(size_t)(k8*8+j)*Nf + n];
  ((uint4*)out)[(size_t)n*K8 + k8] = pack8(f);
}

// ---------- per-edge scalars + CSR in-edge lists ----------
__global__ void k_pre(const int* __restrict__ ei, const int* __restrict__ n2g,
                      const int* __restrict__ nl, const float* __restrict__ sigmas,
                      const float* __restrict__ pos, const float* __restrict__ dn, int E,
                      float* __restrict__ pd, int* __restrict__ cnt, int* __restrict__ inlist){
  int e = blockIdx.x*256 + threadIdx.x;
  if (e >= E) return;
  int r = ei[e], c = ei[E+e];
  float sg = sigmas[nl[n2g[r]]];
  float dx = pos[3*r]-pos[3*c], dy = pos[3*r+1]-pos[3*c+1], dz = pos[3*r+2]-pos[3*c+2];
  float d = sqrtf(dx*dx + dy*dy + dz*dz);
  pd[e] = d + dn[e]*sg;
  int slot = atomicAdd(&cnt[c], 1);
  if (slot < 8) inlist[c*8 + slot] = e;
}

// ---------- x = node_emb[atom_type] ----------
__global__ void k_ninit(const int* __restrict__ at, const float* __restrict__ nemb,
                        float* __restrict__ x, int N){
  int idx = blockIdx.x*256 + threadIdx.x;
  int i = idx >> 6, c = idx & 63;
  if (i >= N) return;
  ((float4*)x)[(size_t)i*64 + c] = ((const float4*)nemb)[(size_t)at[i]*64 + c];
}

// ---------- edge_attr = (relu(pd*W1+b1) @ W2 + b2) * eemb[etype]  [bf16 out], MFMA ----------
// 64 edges/block, 256 thr = 4 waves; wave owns 4 feat-tiles x 4 edge-tiles
__global__ __launch_bounds__(256) void k_attr(
    const float* __restrict__ pd, const float* __restrict__ W1, const float* __restrict__ b1,
    const short* __restrict__ W2T, const float* __restrict__ b2,
    const int* __restrict__ etype, const float* __restrict__ eemb,
    short* __restrict__ attr, int E)
{
  __shared__ uint4 AlsV[64*33];      // hidden [64][264] bf16
  short* Als = (short*)AlsV;
  int tid = threadIdx.x;
  int base = blockIdx.x*64;
  for (int q=0;q<8;q++){
    int lin = q*256 + tid;
    int el = lin >> 5, h8 = (lin & 31)*8;
    int e = base + el;
    float f[8];
    if (e < E){
      float p = pd[e];
      float4 wa = *(const float4*)(W1+h8), wb = *(const float4*)(W1+h8+4);
      float4 ba = *(const float4*)(b1+h8), bb = *(const float4*)(b1+h8+4);
      f[0]=fmaxf(p*wa.x+ba.x,0.f); f[1]=fmaxf(p*wa.y+ba.y,0.f);
      f[2]=fmaxf(p*wa.z+ba.z,0.f); f[3]=fmaxf(p*wa.w+ba.w,0.f);
      f[4]=fmaxf(p*wb.x+bb.x,0.f); f[5]=fmaxf(p*wb.y+bb.y,0.f);
      f[6]=fmaxf(p*wb.z+bb.z,0.f); f[7]=fmaxf(p*wb.w+bb.w,0.f);
    } else { for (int t=0;t<8;t++) f[t]=0.f; }
    ((uint4*)(Als + el*264))[h8>>3] = pack8(f);
  }
  __syncthreads();
  int wv = tid>>6, lane = tid&63, quad = lane>>4, l15 = lane&15;
  f32x4 acc[4][4];
  #pragma unroll
  for (int mt=0;mt<4;mt++) for (int nt=0;nt<4;nt++) acc[mt][nt] = (f32x4)0.f;
  for (int kk=0; kk<256; kk+=32){
    bf16x8 a[4], b[4];
    #pragma unroll
    for (int mt=0;mt<4;mt++){
      int feat = (wv*4+mt)*16 + l15;
      a[mt] = *(const bf16x8*)(W2T + (size_t)feat*256 + kk + quad*8);
    }
    #pragma unroll
    for (int nt=0;nt<4;nt++)
      b[nt] = *(const bf16x8*)(Als + (nt*16+l15)*264 + kk + quad*8);
    #pragma unroll
    for (int mt=0;mt<4;mt++)
      #pragma unroll
      for (int nt=0;nt<4;nt++)
        acc[mt][nt] = MFMA16(a[mt], b[nt], acc[mt][nt]);
  }
  #pragma unroll
  for (int nt=0;nt<4;nt++){
    int e = base + nt*16 + l15;
    if (e < E){
      int et = etype[e];
      #pragma unroll
      for (int mt=0;mt<4;mt++){
        int f0 = (wv*4+mt)*16 + quad*4;
        float4 bb = *(const float4*)(b2 + f0);
        float4 em = *(const float4*)(eemb + (size_t)et*256 + f0);
        float v0 = (acc[mt][nt][0]+bb.x)*em.x, v1 = (acc[mt][nt][1]+bb.y)*em.y;
        float v2 = (acc[mt][nt][2]+bb.z)*em.z, v3 = (acc[mt][nt][3]+bb.w)*em.w;
        uint2 v; v.x = pack2(v0,v1); v.y = pack2(v2,v3);
        *(uint2*)(attr + (size_t)e*256 + f0) = v;
      }
    }
  }
}

// ---------- hin[j] = x[j] + sum_in relu(x[row]+attr)  (gather via CSR) ----------
__global__ void k_agg(const float* __restrict__ x, const uint2* __restrict__ attr2,
                      const int* __restrict__ ei, const int* __restrict__ cnt,
                      const int* __restrict__ inlist, float* __restrict__ hin, int N){
  int tid = threadIdx.x;
  int j = blockIdx.x*4 + (tid >> 6);
  int lane = tid & 63;
  if (j >= N) return;
  const float4* x4 = (const float4*)x;
  float4 a = x4[(size_t)j*64 + lane];
  int deg = min(cnt[j], 8);
  for (int s=0; s<deg; s++){
    int e = inlist[j*8 + s];
    int r = ei[e];
    float4 xr = x4[(size_t)r*64 + lane];
    uint2 av = attr2[(size_t)e*64 + lane];
    a.x += fmaxf(xr.x + __uint_as_float(av.x<<16), 0.f);
    a.y += fmaxf(xr.y + __uint_as_float(av.x&0xffff0000u), 0.f);
    a.z += fmaxf(xr.z + __uint_as_float(av.y<<16), 0.f);
    a.w += fmaxf(xr.w + __uint_as_float(av.y&0xffff0000u), 0.f);
  }
  ((float4*)hin)[(size_t)j*64 + lane] = a;
}

// ---------- fused GIN MLP (MFMA): x += (maybe-relu)(relu(hin@W1+b1)@W2+b2) ----------
// 32 nodes/block; wave owns 4 feat-tiles x 2 node-tiles
__global__ __launch_bounds__(256) void k_mlp(
    const float* __restrict__ hin, const short* __restrict__ W1T, const float* __restrict__ b1,
    const short* __restrict__ W2T, const float* __restrict__ b2,
    float* __restrict__ x, int N, int do_relu)
{
  __shared__ uint4 AlsV[32*33];
  __shared__ uint4 T1V [32*33];
  short* Als = (short*)AlsV;
  short* T1  = (short*)T1V;
  int tid = threadIdx.x;
  int base = blockIdx.x*32;
  for (int q=0;q<4;q++){
    int lin = q*256 + tid;
    int el = lin >> 5, h8 = (lin & 31)*8;
    int r = base + el;
    float f[8];
    if (r < N){
      const float4* p = (const float4*)(hin + (size_t)r*256 + h8);
      float4 a = p[0], b = p[1];
      f[0]=a.x; f[1]=a.y; f[2]=a.z; f[3]=a.w; f[4]=b.x; f[5]=b.y; f[6]=b.z; f[7]=b.w;
    } else { for (int t=0;t<8;t++) f[t]=0.f; }
    ((uint4*)(Als + el*264))[h8>>3] = pack8(f);
  }
  __syncthreads();
  int wv = tid>>6, lane = tid&63, quad = lane>>4, l15 = lane&15;
  f32x4 acc[4][2];
  #pragma unroll
  for (int mt=0;mt<4;mt++) for (int nt=0;nt<2;nt++) acc[mt][nt] = (f32x4)0.f;
  for (int kk=0; kk<256; kk+=32){
    bf16x8 a[4], b[2];
    #pragma unroll
    for (int mt=0;mt<4;mt++)
      a[mt] = *(const bf16x8*)(W1T + (size_t)((wv*4+mt)*16 + l15)*256 + kk + quad*8);
    #pragma unroll
    for (int nt=0;nt<2;nt++)
      b[nt] = *(const bf16x8*)(Als + (nt*16+l15)*264 + kk + quad*8);
    #pragma unroll
    for (int mt=0;mt<4;mt++)
      #pragma unroll
      for (int nt=0;nt<2;nt++)
        acc[mt][nt] = MFMA16(a[mt], b[nt], acc[mt][nt]);
  }
  #pragma unroll
  for (int mt=0;mt<4;mt++){
    int f0 = (wv*4+mt)*16 + quad*4;
    float4 bb = *(const float4*)(b1 + f0);
    #pragma unroll
    for (int nt=0;nt<2;nt++){
      int nl = nt*16 + l15;
      float v0 = fmaxf(acc[mt][nt][0]+bb.x,0.f), v1 = fmaxf(acc[mt][nt][1]+bb.y,0.f);
      float v2 = fmaxf(acc[mt][nt][2]+bb.z,0.f), v3 = fmaxf(acc[mt][nt][3]+bb.w,0.f);
      uint2 v; v.x = pack2(v0,v1); v.y = pack2(v2,v3);
      *(uint2*)(T1 + nl*264 + f0) = v;
    }
  }
  __syncthreads();
  f32x4 acc2[4][2];
  #pragma unroll
  for (int mt=0;mt<4;mt++) for (int nt=0;nt<2;nt++) acc2[mt][nt] = (f32x4)0.f;
  for (int kk=0; kk<256; kk+=32){
    bf16x8 a[4], b[2];
    #pragma unroll
    for (int mt=0;mt<4;mt++)
      a[mt] = *(const bf16x8*)(W2T + (size_t)((wv*4+mt)*16 + l15)*256 + kk + quad*8);
    #pragma unroll
    for (int nt=0;nt<2;nt++)
      b[nt] = *(const bf16x8*)(T1 + (nt*16+l15)*264 + kk + quad*8);
    #pragma unroll
    for (int mt=0;mt<4;mt++)
      #pragma unroll
      for (int nt=0;nt<2;nt++)
        acc2[mt][nt] = MFMA16(a[mt], b[nt], acc2[mt][nt]);
  }
  #pragma unroll
  for (int mt=0;mt<4;mt++){
    int f0 = (wv*4+mt)*16 + quad*4;
    float4 bb = *(const float4*)(b2 + f0);
    #pragma unroll
    for (int nt=0;nt<2;nt++){
      int r = base + nt*16 + l15;
      if (r < N){
        float* px = x + (size_t)r*256 + f0;
        float4 xv = *(float4*)px;
        float h0 = acc2[mt][nt][0]+bb.x, h1 = acc2[mt][nt][1]+bb.y;
        float h2 = acc2[mt][nt][2]+bb.z, h3 = acc2[mt][nt][3]+bb.w;
        if (do_relu){ h0=fmaxf(h0,0.f); h1=fmaxf(h1,0.f); h2=fmaxf(h2,0.f); h3=fmaxf(h3,0.f); }
        xv.x += h0; xv.y += h1; xv.z += h2; xv.w += h3;
        *(float4*)px = xv;
      }
    }
  }
}

// ---------- fused head (MFMA): feat=[x_r*x_c, attr] -> 512->256->128->1 -> loss ----------
// 32 edges/block; L1: wave owns 4 feat-tiles x 2 edge-tiles; L2: 2 x 2
__global__ __launch_bounds__(256) void k_head(
    const float* __restrict__ x, const short* __restrict__ attrS,
    const int* __restrict__ ei, const int* __restrict__ n2g,
    const short* __restrict__ W1T, const float* __restrict__ ob1,
    const short* __restrict__ W2T, const float* __restrict__ ob2,
    const float* __restrict__ W3, const float* __restrict__ ob3,
    const float* __restrict__ dnoise, float* __restrict__ out, int E)
{
  __shared__ uint4 FV [32*65];   // feat [32][520] bf16
  __shared__ uint4 T1V[32*33];   // [32][264] bf16
  __shared__ uint4 T2V[32*17];   // [32][136] bf16
  __shared__ float W3s[128];
  short* F  = (short*)FV;
  short* T1 = (short*)T1V;
  short* T2 = (short*)T2V;
  int tid = threadIdx.x;
  int base = blockIdx.x*32;
  for (int q=0;q<8;q++){
    int lin = q*256 + tid;
    int el = lin >> 6, c8 = lin & 63;
    int h8 = c8*8;
    int e = base + el;
    uint4 v;
    if (e < E){
      if (h8 < 256){
        int r = ei[e], c = ei[E+e];
        const float4* xr = (const float4*)(x + (size_t)r*256 + h8);
        const float4* xc = (const float4*)(x + (size_t)c*256 + h8);
        float4 a0 = xr[0], a1 = xr[1], b0 = xc[0], b1 = xc[1];
        float f[8] = {a0.x*b0.x, a0.y*b0.y, a0.z*b0.z, a0.w*b0.w,
                      a1.x*b1.x, a1.y*b1.y, a1.z*b1.z, a1.w*b1.w};
        v = pack8(f);
      } else {
        v = ((const uint4*)attrS)[((size_t)e*256 + (h8-256)) >> 3];
      }
    } else v = make_uint4(0,0,0,0);
    ((uint4*)(F + el*520))[c8] = v;
  }
  if (tid < 128) W3s[tid] = W3[tid];
  __syncthreads();
  int wv = tid>>6, lane = tid&63, quad = lane>>4, l15 = lane&15;
  // ---- L1: K=512, M=256, N=32 ----
  f32x4 acc[4][2];
  #pragma unroll
  for (int mt=0;mt<4;mt++) for (int nt=0;nt<2;nt++) acc[mt][nt] = (f32x4)0.f;
  for (int kk=0; kk<512; kk+=32){
    bf16x8 a[4], b[2];
    #pragma unroll
    for (int mt=0;mt<4;mt++)
      a[mt] = *(const bf16x8*)(W1T + (size_t)((wv*4+mt)*16 + l15)*512 + kk + quad*8);
    #pragma unroll
    for (int nt=0;nt<2;nt++)
      b[nt] = *(const bf16x8*)(F + (nt*16+l15)*520 + kk + quad*8);
    #pragma unroll
    for (int mt=0;mt<4;mt++)
      #pragma unroll
      for (int nt=0;nt<2;nt++)
        acc[mt][nt] = MFMA16(a[mt], b[nt], acc[mt][nt]);
  }
  #pragma unroll
  for (int mt=0;mt<4;mt++){
    int f0 = (wv*4+mt)*16 + quad*4;
    float4 bb = *(const float4*)(ob1 + f0);
    #pragma unroll
    for (int nt=0;nt<2;nt++){
      int nl = nt*16 + l15;
      float v0 = fmaxf(acc[mt][nt][0]+bb.x,0.f), v1 = fmaxf(acc[mt][nt][1]+bb.y,0.f);
      float v2 = fmaxf(acc[mt][nt][2]+bb.z,0.f), v3 = fmaxf(acc[mt][nt][3]+bb.w,0.f);
      uint2 v; v.x = pack2(v0,v1); v.y = pack2(v2,v3);
      *(uint2*)(T1 + nl*264 + f0) = v;
    }
  }
  __syncthreads();
  // ---- L2: K=256, M=128, N=32 ----
  f32x4 acc2[2][2];
  #pragma unroll
  for (int mt=0;mt<2;mt++) for (int nt=0;nt<2;nt++) acc2[mt][nt] = (f32x4)0.f;
  for (int kk=0; kk<256; kk+=32){
    bf16x8 a[2], b[2];
    #pragma unroll
    for (int mt=0;mt<2;mt++)
      a[mt] = *(const bf16x8*)(W2T + (size_t)((wv*2+mt)*16 + l15)*256 + kk + quad*8);
    #pragma unroll
    for (int nt=0;nt<2;nt++)
      b[nt] = *(const bf16x8*)(T1 + (nt*16+l15)*264 + kk + quad*8);
    #pragma unroll
    for (int mt=0;mt<2;mt++)
      #pragma unroll
      for (int nt=0;nt<2;nt++)
        acc2[mt][nt] = MFMA16(a[mt], b[nt], acc2[mt][nt]);
  }
  #pragma unroll
  for (int mt=0;mt<2;mt++){
    int f0 = (wv*2+mt)*16 + quad*4;
    float4 bb = *(const float4*)(ob2 + f0);
    #pragma unroll
    for (int nt=0;nt<2;nt++){
      int nl = nt*16 + l15;
      float v0 = fmaxf(acc2[mt][nt][0]+bb.x,0.f), v1 = fmaxf(acc2[mt][nt][1]+bb.y,0.f);
      float v2 = fmaxf(acc2[mt][nt][2]+bb.z,0.f), v3 = fmaxf(acc2[mt][nt][3]+bb.w,0.f);
      uint2 v; v.x = pack2(v0,v1); v.y = pack2(v2,v3);
      *(uint2*)(T2 + nl*136 + f0) = v;
    }
  }
  __syncthreads();
  // ---- L3: K=128, N=1 + loss ----
  int el = tid >> 3, part = tid & 7;
  float s = 0.f;
  {
    const short* t2r = T2 + el*136 + part*16;
    bf16x8 v0 = *(const bf16x8*)(t2r);
    bf16x8 v1 = *(const bf16x8*)(t2r + 8);
    int c0 = part*16;
    #pragma unroll
    for (int c=0;c<8;c++){ s += bf2f(v0[c])*W3s[c0+c]; s += bf2f(v1[c])*W3s[c0+8+c]; }
  }
  s += __shfl_xor(s, 1);
  s += __shfl_xor(s, 2);
  s += __shfl_xor(s, 4);
  if (part == 0){
    int e = base + el;
    if (e < E){
      float sv = s + ob3[0];
      float dn = dnoise[e];
      float l = 0.5f*(sv + dn)*(sv + dn);
      atomicAdd(&out[n2g[ei[e]]], l);
    }
  }
}

// =========================== host ===========================
static inline size_t alignup(size_t v){ return (v + 255) & ~(size_t)255; }

extern "C" void kernel_launch(void* const* d_in, const int* in_sizes, int n_in,
                              void* d_out, int out_size, void* d_ws, size_t ws_size,
                              hipStream_t stream) {
  const int*   at    = (const int*)  d_in[0];
  const int*   ei    = (const int*)  d_in[1];
  const int*   etype = (const int*)  d_in[2];
  const int*   n2g   = (const int*)  d_in[3];
  const int*   nl    = (const int*)  d_in[4];
  const float* pos   = (const float*)d_in[5];
  const float* dnoi  = (const float*)d_in[6];
  const float* sig   = (const float*)d_in[7];
  const float* nemb  = (const float*)d_in[8];
  const float* eemb  = (const float*)d_in[9];
  const float* inW1  = (const float*)d_in[10];
  const float* inb1  = (const float*)d_in[11];
  const float* inW2  = (const float*)d_in[12];
  const float* inb2  = (const float*)d_in[13];
  const float* gW1   = (const float*)d_in[14];
  const float* gb1   = (const float*)d_in[15];
  const float* gW2   = (const float*)d_in[16];
  const float* gb2   = (const float*)d_in[17];
  const float* oW1   = (const float*)d_in[18];
  const float* ob1   = (const float*)d_in[19];
  const float* oW2   = (const float*)d_in[20];
  const float* ob2   = (const float*)d_in[21];
  const float* oW3   = (const float*)d_in[22];
  const float* ob3   = (const float*)d_in[23];
  float* out = (float*)d_out;

  const int N = in_sizes[0];
  const int E = in_sizes[2];
  const int G = in_sizes[4];
  const int H = 256;

  char* w = (char*)d_ws;
  size_t off = 0;
  size_t o_attr  = off; off = alignup(off + (size_t)E*H*2);
  size_t o_x     = off; off = alignup(off + (size_t)N*H*4);
  size_t o_hin   = off; off = alignup(off + (size_t)N*H*4);
  size_t o_pd    = off; off = alignup(off + (size_t)E*4);
  size_t o_cnt   = off; off = alignup(off + (size_t)N*4);
  size_t o_inl   = off; off = alignup(off + (size_t)N*8*4);
  size_t o_w2t   = off; off = alignup(off + (size_t)H*H*2);
  size_t o_gw1t  = off; off = alignup(off + (size_t)4*H*H*2);
  size_t o_gw2t  = off; off = alignup(off + (size_t)4*H*H*2);
  size_t o_ow1t  = off; off = alignup(off + (size_t)H*2*H*2);
  size_t o_ow2t  = off; off = alignup(off + (size_t)(H/2)*H*2);
  (void)ws_size; (void)n_in; (void)out_size;

  short* attrS = (short*)(w + o_attr);
  float* x     = (float*)(w + o_x);
  float* hin   = (float*)(w + o_hin);
  float* pd    = (float*)(w + o_pd);
  int*   cnt   = (int*)  (w + o_cnt);
  int*   inl   = (int*)  (w + o_inl);
  short* w2t   = (short*)(w + o_w2t);
  short* gw1t  = (short*)(w + o_gw1t);
  short* gw2t  = (short*)(w + o_gw2t);
  short* ow1t  = (short*)(w + o_ow1t);
  short* ow2t  = (short*)(w + o_ow2t);

  hipMemsetAsync(cnt, 0, (size_t)N*4, stream);
  hipMemsetAsync(out, 0, (size_t)G*4, stream);

  // transposed bf16 weight conversions
  {
    int n8 = H*H/8;   // 8192 threads for 256x256
    k_cvtT<<<(n8+255)/256, 256, 0, stream>>>(inW2, w2t, H, H);
    for (int c=0;c<4;c++){
      k_cvtT<<<(n8+255)/256, 256, 0, stream>>>(gW1 + (size_t)c*H*H, gw1t + (size_t)c*H*H, H, H);
      k_cvtT<<<(n8+255)/256, 256, 0, stream>>>(gW2 + (size_t)c*H*H, gw2t + (size_t)c*H*H, H, H);
    }
    int n1 = H*2*H/8;
    k_cvtT<<<(n1+255)/256, 256, 0, stream>>>(oW1, ow1t, 2*H, H);      // [512][256] -> [256][512]
    int n2 = (H/2)*H/8;
    k_cvtT<<<(n2+255)/256, 256, 0, stream>>>(oW2, ow2t, H, H/2);      // [256][128] -> [128][256]
  }

  k_pre<<<(E+255)/256, 256, 0, stream>>>(ei, n2g, nl, sig, pos, dnoi, E, pd, cnt, inl);
  k_ninit<<<(N*64+255)/256, 256, 0, stream>>>(at, nemb, x, N);
  k_attr<<<(E+63)/64, 256, 0, stream>>>(pd, inW1, inb1, w2t, inb2, etype, eemb, attrS, E);

  for (int c=0; c<4; c++){
    k_agg<<<(N+3)/4, 256, 0, stream>>>(x, (const uint2*)attrS, ei, cnt, inl, hin, N);
    k_mlp<<<(N+31)/32, 256, 0, stream>>>(hin,
        gw1t + (size_t)c*H*H, gb1 + (size_t)c*H,
        gw2t + (size_t)c*H*H, gb2 + (size_t)c*H,
        x, N, (c<3) ? 1 : 0);
  }

  k_head<<<(E+31)/32, 256, 0, stream>>>(x, attrS, ei, n2g,
      ow1t, ob1, ow2t, ob2, oW3, ob3, dnoi, out, E);
}

// Round 3
// 918.275 us; speedup vs baseline: 2.6083x; 1.1442x over previous
//
#include <hip/hip_runtime.h>
#include <math.h>

typedef unsigned int u32;
typedef __attribute__((ext_vector_type(8))) short bf16x8;
typedef __attribute__((ext_vector_type(4))) float f32x4;

#define MFMA16(a,b,c) __builtin_amdgcn_mfma_f32_16x16x32_bf16(a,b,c,0,0,0)

// ---------- bf16 helpers ----------
__device__ inline u32 bf16r(float x){
  u32 u = __float_as_uint(x);
  return (u + 0x7fffu + ((u >> 16) & 1u)) >> 16;
}
__device__ inline u32 pack2(float a, float b){ return bf16r(a) | (bf16r(b) << 16); }
__device__ inline uint4 pack8(const float* f){
  uint4 v; v.x = pack2(f[0],f[1]); v.y = pack2(f[2],f[3]);
  v.z = pack2(f[4],f[5]); v.w = pack2(f[6],f[7]); return v;
}
__device__ inline float bf2f(short s){ return __uint_as_float(((u32)(unsigned short)s) << 16); }

// ---------- f32 [K][Nf] -> bf16 transposed [Nf][K] ----------
__global__ void k_cvtT(const float* __restrict__ in, short* __restrict__ out, int K, int Nf){
  int tid = blockIdx.x*256 + threadIdx.x;
  int K8 = K >> 3;
  if (tid >= Nf*K8) return;
  int n = tid / K8, k8 = tid % K8;
  float f[8];
  #pragma unroll
  for (int j=0;j<8;j++) f[j] = in[(size_t)(k8*8+j)*Nf + n];
  ((uint4*)out)[(size_t)n*K8 + k8] = pack8(f);
}

// ---------- per-edge scalars + CSR in-edge lists ----------
__global__ void k_pre(const int* __restrict__ ei, const int* __restrict__ n2g,
                      const int* __restrict__ nl, const float* __restrict__ sigmas,
                      const float* __restrict__ pos, const float* __restrict__ dn, int E,
                      float* __restrict__ pd, int* __restrict__ cnt, int* __restrict__ inlist){
  int e = blockIdx.x*256 + threadIdx.x;
  if (e >= E) return;
  int r = ei[e], c = ei[E+e];
  float sg = sigmas[nl[n2g[r]]];
  float dx = pos[3*r]-pos[3*c], dy = pos[3*r+1]-pos[3*c+1], dz = pos[3*r+2]-pos[3*c+2];
  float d = sqrtf(dx*dx + dy*dy + dz*dz);
  pd[e] = d + dn[e]*sg;
  int slot = atomicAdd(&cnt[c], 1);
  if (slot < 8) inlist[c*8 + slot] = e;
}

// ---------- x = node_emb[atom_type] ----------
__global__ void k_ninit(const int* __restrict__ at, const float* __restrict__ nemb,
                        float* __restrict__ x, int N){
  int idx = blockIdx.x*256 + threadIdx.x;
  int i = idx >> 6, c = idx & 63;
  if (i >= N) return;
  ((float4*)x)[(size_t)i*64 + c] = ((const float4*)nemb)[(size_t)at[i]*64 + c];
}

// ---------- edge_attr = (relu(pd*W1+b1) @ W2 + b2) * eemb[etype]  [bf16 out], MFMA ----------
__global__ __launch_bounds__(256,3) void k_attr(
    const float* __restrict__ pd, const float* __restrict__ W1, const float* __restrict__ b1,
    const short* __restrict__ W2T, const float* __restrict__ b2,
    const int* __restrict__ etype, const float* __restrict__ eemb,
    short* __restrict__ attr, int E)
{
  __shared__ uint4 AlsV[64*33];      // hidden [64][264] bf16
  short* Als = (short*)AlsV;
  int tid = threadIdx.x;
  int base = blockIdx.x*64;
  for (int q=0;q<8;q++){
    int lin = q*256 + tid;
    int el = lin >> 5, h8 = (lin & 31)*8;
    int e = base + el;
    float f[8];
    if (e < E){
      float p = pd[e];
      float4 wa = *(const float4*)(W1+h8), wb = *(const float4*)(W1+h8+4);
      float4 ba = *(const float4*)(b1+h8), bb = *(const float4*)(b1+h8+4);
      f[0]=fmaxf(p*wa.x+ba.x,0.f); f[1]=fmaxf(p*wa.y+ba.y,0.f);
      f[2]=fmaxf(p*wa.z+ba.z,0.f); f[3]=fmaxf(p*wa.w+ba.w,0.f);
      f[4]=fmaxf(p*wb.x+bb.x,0.f); f[5]=fmaxf(p*wb.y+bb.y,0.f);
      f[6]=fmaxf(p*wb.z+bb.z,0.f); f[7]=fmaxf(p*wb.w+bb.w,0.f);
    } else { for (int t=0;t<8;t++) f[t]=0.f; }
    ((uint4*)(Als + el*264))[h8>>3] = pack8(f);
  }
  __syncthreads();
  int wv = tid>>6, lane = tid&63, quad = lane>>4, l15 = lane&15;
  f32x4 acc[4][4];
  #pragma unroll
  for (int mt=0;mt<4;mt++) for (int nt=0;nt<4;nt++) acc[mt][nt] = (f32x4)0.f;
  #pragma unroll 2
  for (int kk=0; kk<256; kk+=32){
    bf16x8 a[4], b[4];
    #pragma unroll
    for (int mt=0;mt<4;mt++)
      a[mt] = *(const bf16x8*)(W2T + (size_t)((wv*4+mt)*16 + l15)*256 + kk + quad*8);
    #pragma unroll
    for (int nt=0;nt<4;nt++)
      b[nt] = *(const bf16x8*)(Als + (nt*16+l15)*264 + kk + quad*8);
    #pragma unroll
    for (int mt=0;mt<4;mt++)
      #pragma unroll
      for (int nt=0;nt<4;nt++)
        acc[mt][nt] = MFMA16(a[mt], b[nt], acc[mt][nt]);
  }
  #pragma unroll
  for (int nt=0;nt<4;nt++){
    int e = base + nt*16 + l15;
    if (e < E){
      int et = etype[e];
      #pragma unroll
      for (int mt=0;mt<4;mt++){
        int f0 = (wv*4+mt)*16 + quad*4;
        float4 bb = *(const float4*)(b2 + f0);
        float4 em = *(const float4*)(eemb + (size_t)et*256 + f0);
        float v0 = (acc[mt][nt][0]+bb.x)*em.x, v1 = (acc[mt][nt][1]+bb.y)*em.y;
        float v2 = (acc[mt][nt][2]+bb.z)*em.z, v3 = (acc[mt][nt][3]+bb.w)*em.w;
        uint2 v; v.x = pack2(v0,v1); v.y = pack2(v2,v3);
        *(uint2*)(attr + (size_t)e*256 + f0) = v;
      }
    }
  }
}

// ---------- fused GIN conv (agg gather + MLP MFMA): x_out = x_in + MLP(x_in + agg) ----------
// 32 nodes/block; staging does the CSR gather inline (no hin buffer).
__global__ __launch_bounds__(256,4) void k_mlp(
    const float* __restrict__ x_in, const uint2* __restrict__ attr2,
    const int* __restrict__ ei, const int* __restrict__ cnt, const int* __restrict__ inlist,
    const short* __restrict__ W1T, const float* __restrict__ b1,
    const short* __restrict__ W2T, const float* __restrict__ b2,
    float* __restrict__ x_out, int N, int do_relu)
{
  __shared__ uint4 SMEMV[32*33];    // Als [32][264]; T1 aliases after barrier
  short* Als = (short*)SMEMV;
  short* T1  = (short*)SMEMV;
  int tid = threadIdx.x;
  int base = blockIdx.x*32;
  // --- staging: hin[j] = x_in[j] + sum_in relu(x_in[row]+attr), 8 thr/node x 32 feats ---
  {
    int el = tid >> 3, ch = tid & 7;
    int j = base + el;
    if (j < N){
      float f[32];
      const float4* xj = (const float4*)x_in + (size_t)j*64 + ch*8;
      #pragma unroll
      for (int i=0;i<8;i++){ float4 v = xj[i]; f[i*4]=v.x; f[i*4+1]=v.y; f[i*4+2]=v.z; f[i*4+3]=v.w; }
      int deg = min(cnt[j], 8);
      for (int s=0; s<deg; s++){
        int e = inlist[j*8 + s];
        int r = ei[e];
        const float4* xr = (const float4*)x_in + (size_t)r*64 + ch*8;
        const uint2* av = attr2 + (size_t)e*64 + ch*8;
        #pragma unroll
        for (int i=0;i<8;i++){
          float4 xv = xr[i]; uint2 a = av[i];
          f[i*4]   += fmaxf(xv.x + __uint_as_float(a.x<<16), 0.f);
          f[i*4+1] += fmaxf(xv.y + __uint_as_float(a.x&0xffff0000u), 0.f);
          f[i*4+2] += fmaxf(xv.z + __uint_as_float(a.y<<16), 0.f);
          f[i*4+3] += fmaxf(xv.w + __uint_as_float(a.y&0xffff0000u), 0.f);
        }
      }
      uint4* dst = (uint4*)(Als + el*264 + ch*32);
      #pragma unroll
      for (int q=0;q<4;q++) dst[q] = pack8(f + q*8);
    }
  }
  __syncthreads();
  int wv = tid>>6, lane = tid&63, quad = lane>>4, l15 = lane&15;
  f32x4 acc[4][2];
  #pragma unroll
  for (int mt=0;mt<4;mt++) for (int nt=0;nt<2;nt++) acc[mt][nt] = (f32x4)0.f;
  #pragma unroll 2
  for (int kk=0; kk<256; kk+=32){
    bf16x8 a[4], b[2];
    #pragma unroll
    for (int mt=0;mt<4;mt++)
      a[mt] = *(const bf16x8*)(W1T + (size_t)((wv*4+mt)*16 + l15)*256 + kk + quad*8);
    #pragma unroll
    for (int nt=0;nt<2;nt++)
      b[nt] = *(const bf16x8*)(Als + (nt*16+l15)*264 + kk + quad*8);
    #pragma unroll
    for (int mt=0;mt<4;mt++)
      #pragma unroll
      for (int nt=0;nt<2;nt++)
        acc[mt][nt] = MFMA16(a[mt], b[nt], acc[mt][nt]);
  }
  __syncthreads();   // all waves done reading Als; T1 aliases it
  #pragma unroll
  for (int mt=0;mt<4;mt++){
    int f0 = (wv*4+mt)*16 + quad*4;
    float4 bb = *(const float4*)(b1 + f0);
    #pragma unroll
    for (int nt=0;nt<2;nt++){
      int nl = nt*16 + l15;
      float v0 = fmaxf(acc[mt][nt][0]+bb.x,0.f), v1 = fmaxf(acc[mt][nt][1]+bb.y,0.f);
      float v2 = fmaxf(acc[mt][nt][2]+bb.z,0.f), v3 = fmaxf(acc[mt][nt][3]+bb.w,0.f);
      uint2 v; v.x = pack2(v0,v1); v.y = pack2(v2,v3);
      *(uint2*)(T1 + nl*264 + f0) = v;
    }
  }
  __syncthreads();
  f32x4 acc2[4][2];
  #pragma unroll
  for (int mt=0;mt<4;mt++) for (int nt=0;nt<2;nt++) acc2[mt][nt] = (f32x4)0.f;
  #pragma unroll 2
  for (int kk=0; kk<256; kk+=32){
    bf16x8 a[4], b[2];
    #pragma unroll
    for (int mt=0;mt<4;mt++)
      a[mt] = *(const bf16x8*)(W2T + (size_t)((wv*4+mt)*16 + l15)*256 + kk + quad*8);
    #pragma unroll
    for (int nt=0;nt<2;nt++)
      b[nt] = *(const bf16x8*)(T1 + (nt*16+l15)*264 + kk + quad*8);
    #pragma unroll
    for (int mt=0;mt<4;mt++)
      #pragma unroll
      for (int nt=0;nt<2;nt++)
        acc2[mt][nt] = MFMA16(a[mt], b[nt], acc2[mt][nt]);
  }
  #pragma unroll
  for (int mt=0;mt<4;mt++){
    int f0 = (wv*4+mt)*16 + quad*4;
    float4 bb = *(const float4*)(b2 + f0);
    #pragma unroll
    for (int nt=0;nt<2;nt++){
      int r = base + nt*16 + l15;
      if (r < N){
        const float* pin = x_in + (size_t)r*256 + f0;
        float* pout = x_out + (size_t)r*256 + f0;
        float4 xv = *(const float4*)pin;
        float h0 = acc2[mt][nt][0]+bb.x, h1 = acc2[mt][nt][1]+bb.y;
        float h2 = acc2[mt][nt][2]+bb.z, h3 = acc2[mt][nt][3]+bb.w;
        if (do_relu){ h0=fmaxf(h0,0.f); h1=fmaxf(h1,0.f); h2=fmaxf(h2,0.f); h3=fmaxf(h3,0.f); }
        xv.x += h0; xv.y += h1; xv.z += h2; xv.w += h3;
        *(float4*)pout = xv;
      }
    }
  }
}

// ---------- fused head (MFMA): feat=[x_r*x_c, attr] -> 512->256->128->1 -> loss ----------
// 64 edges/block; T1/T2 alias the F region after L1 completes.
__global__ __launch_bounds__(256,2) void k_head(
    const float* __restrict__ x, const short* __restrict__ attrS,
    const int* __restrict__ ei, const int* __restrict__ n2g,
    const short* __restrict__ W1T, const float* __restrict__ ob1,
    const short* __restrict__ W2T, const float* __restrict__ ob2,
    const float* __restrict__ W3, const float* __restrict__ ob3,
    const float* __restrict__ dnoise, float* __restrict__ out, int E)
{
  __shared__ short SMEM[64*520];   // F [64][520]; after L1: T1 [64][264] @0, T2 [64][136] @64*264
  __shared__ float W3s[128];
  short* F  = SMEM;
  short* T1 = SMEM;
  short* T2 = SMEM + 64*264;
  int tid = threadIdx.x;
  int base = blockIdx.x*64;
  for (int q=0;q<16;q++){
    int lin = q*256 + tid;
    int el = lin >> 6, c8 = lin & 63;
    int h8 = c8*8;
    int e = base + el;
    uint4 v;
    if (e < E){
      if (h8 < 256){
        int r = ei[e], c = ei[E+e];
        const float4* xr = (const float4*)(x + (size_t)r*256 + h8);
        const float4* xc = (const float4*)(x + (size_t)c*256 + h8);
        float4 a0 = xr[0], a1 = xr[1], b0 = xc[0], b1 = xc[1];
        float f[8] = {a0.x*b0.x, a0.y*b0.y, a0.z*b0.z, a0.w*b0.w,
                      a1.x*b1.x, a1.y*b1.y, a1.z*b1.z, a1.w*b1.w};
        v = pack8(f);
      } else {
        v = ((const uint4*)attrS)[((size_t)e*256 + (h8-256)) >> 3];
      }
    } else v = make_uint4(0,0,0,0);
    ((uint4*)(F + el*520))[c8] = v;
  }
  if (tid < 128) W3s[tid] = W3[tid];
  __syncthreads();
  int wv = tid>>6, lane = tid&63, quad = lane>>4, l15 = lane&15;
  // ---- L1: K=512, M=256, N=64 ----
  f32x4 acc[4][4];
  #pragma unroll
  for (int mt=0;mt<4;mt++) for (int nt=0;nt<4;nt++) acc[mt][nt] = (f32x4)0.f;
  #pragma unroll 2
  for (int kk=0; kk<512; kk+=32){
    bf16x8 a[4], b[4];
    #pragma unroll
    for (int mt=0;mt<4;mt++)
      a[mt] = *(const bf16x8*)(W1T + (size_t)((wv*4+mt)*16 + l15)*512 + kk + quad*8);
    #pragma unroll
    for (int nt=0;nt<4;nt++)
      b[nt] = *(const bf16x8*)(F + (nt*16+l15)*520 + kk + quad*8);
    #pragma unroll
    for (int mt=0;mt<4;mt++)
      #pragma unroll
      for (int nt=0;nt<4;nt++)
        acc[mt][nt] = MFMA16(a[mt], b[nt], acc[mt][nt]);
  }
  __syncthreads();   // all waves done reading F; T1 aliases it
  #pragma unroll
  for (int mt=0;mt<4;mt++){
    int f0 = (wv*4+mt)*16 + quad*4;
    float4 bb = *(const float4*)(ob1 + f0);
    #pragma unroll
    for (int nt=0;nt<4;nt++){
      int nl = nt*16 + l15;
      float v0 = fmaxf(acc[mt][nt][0]+bb.x,0.f), v1 = fmaxf(acc[mt][nt][1]+bb.y,0.f);
      float v2 = fmaxf(acc[mt][nt][2]+bb.z,0.f), v3 = fmaxf(acc[mt][nt][3]+bb.w,0.f);
      uint2 v; v.x = pack2(v0,v1); v.y = pack2(v2,v3);
      *(uint2*)(T1 + nl*264 + f0) = v;
    }
  }
  __syncthreads();
  // ---- L2: K=256, M=128, N=64 ----
  f32x4 acc2[2][4];
  #pragma unroll
  for (int mt=0;mt<2;mt++) for (int nt=0;nt<4;nt++) acc2[mt][nt] = (f32x4)0.f;
  #pragma unroll 2
  for (int kk=0; kk<256; kk+=32){
    bf16x8 a[2], b[4];
    #pragma unroll
    for (int mt=0;mt<2;mt++)
      a[mt] = *(const bf16x8*)(W2T + (size_t)((wv*2+mt)*16 + l15)*256 + kk + quad*8);
    #pragma unroll
    for (int nt=0;nt<4;nt++)
      b[nt] = *(const bf16x8*)(T1 + (nt*16+l15)*264 + kk + quad*8);
    #pragma unroll
    for (int mt=0;mt<2;mt++)
      #pragma unroll
      for (int nt=0;nt<4;nt++)
        acc2[mt][nt] = MFMA16(a[mt], b[nt], acc2[mt][nt]);
  }
  #pragma unroll
  for (int mt=0;mt<2;mt++){
    int f0 = (wv*2+mt)*16 + quad*4;
    float4 bb = *(const float4*)(ob2 + f0);
    #pragma unroll
    for (int nt=0;nt<4;nt++){
      int nl = nt*16 + l15;
      float v0 = fmaxf(acc2[mt][nt][0]+bb.x,0.f), v1 = fmaxf(acc2[mt][nt][1]+bb.y,0.f);
      float v2 = fmaxf(acc2[mt][nt][2]+bb.z,0.f), v3 = fmaxf(acc2[mt][nt][3]+bb.w,0.f);
      uint2 v; v.x = pack2(v0,v1); v.y = pack2(v2,v3);
      *(uint2*)(T2 + nl*136 + f0) = v;
    }
  }
  __syncthreads();
  // ---- L3: K=128, N=1 + loss; 4 threads/edge, 32 k each ----
  int el = tid >> 2, part = tid & 3;
  float s = 0.f;
  {
    const short* t2r = T2 + el*136 + part*32;
    int c0 = part*32;
    #pragma unroll
    for (int q=0;q<4;q++){
      bf16x8 v = *(const bf16x8*)(t2r + q*8);
      #pragma unroll
      for (int c=0;c<8;c++) s += bf2f(v[c])*W3s[c0+q*8+c];
    }
  }
  s += __shfl_xor(s, 1);
  s += __shfl_xor(s, 2);
  if (part == 0){
    int e = base + el;
    if (e < E){
      float sv = s + ob3[0];
      float dn = dnoise[e];
      float l = 0.5f*(sv + dn)*(sv + dn);
      atomicAdd(&out[n2g[ei[e]]], l);
    }
  }
}

// =========================== host ===========================
static inline size_t alignup(size_t v){ return (v + 255) & ~(size_t)255; }

extern "C" void kernel_launch(void* const* d_in, const int* in_sizes, int n_in,
                              void* d_out, int out_size, void* d_ws, size_t ws_size,
                              hipStream_t stream) {
  const int*   at    = (const int*)  d_in[0];
  const int*   ei    = (const int*)  d_in[1];
  const int*   etype = (const int*)  d_in[2];
  const int*   n2g   = (const int*)  d_in[3];
  const int*   nl    = (const int*)  d_in[4];
  const float* pos   = (const float*)d_in[5];
  const float* dnoi  = (const float*)d_in[6];
  const float* sig   = (const float*)d_in[7];
  const float* nemb  = (const float*)d_in[8];
  const float* eemb  = (const float*)d_in[9];
  const float* inW1  = (const float*)d_in[10];
  const float* inb1  = (const float*)d_in[11];
  const float* inW2  = (const float*)d_in[12];
  const float* inb2  = (const float*)d_in[13];
  const float* gW1   = (const float*)d_in[14];
  const float* gb1   = (const float*)d_in[15];
  const float* gW2   = (const float*)d_in[16];
  const float* gb2   = (const float*)d_in[17];
  const float* oW1   = (const float*)d_in[18];
  const float* ob1   = (const float*)d_in[19];
  const float* oW2   = (const float*)d_in[20];
  const float* ob2   = (const float*)d_in[21];
  const float* oW3   = (const float*)d_in[22];
  const float* ob3   = (const float*)d_in[23];
  float* out = (float*)d_out;

  const int N = in_sizes[0];
  const int E = in_sizes[2];
  const int G = in_sizes[4];
  const int H = 256;

  char* w = (char*)d_ws;
  size_t off = 0;
  size_t o_attr  = off; off = alignup(off + (size_t)E*H*2);
  size_t o_xA    = off; off = alignup(off + (size_t)N*H*4);
  size_t o_xB    = off; off = alignup(off + (size_t)N*H*4);
  size_t o_pd    = off; off = alignup(off + (size_t)E*4);
  size_t o_cnt   = off; off = alignup(off + (size_t)N*4);
  size_t o_inl   = off; off = alignup(off + (size_t)N*8*4);
  size_t o_w2t   = off; off = alignup(off + (size_t)H*H*2);
  size_t o_gw1t  = off; off = alignup(off + (size_t)4*H*H*2);
  size_t o_gw2t  = off; off = alignup(off + (size_t)4*H*H*2);
  size_t o_ow1t  = off; off = alignup(off + (size_t)H*2*H*2);
  size_t o_ow2t  = off; off = alignup(off + (size_t)(H/2)*H*2);
  (void)ws_size; (void)n_in; (void)out_size;

  short* attrS = (short*)(w + o_attr);
  float* xA    = (float*)(w + o_xA);
  float* xB    = (float*)(w + o_xB);
  float* pd    = (float*)(w + o_pd);
  int*   cnt   = (int*)  (w + o_cnt);
  int*   inl   = (int*)  (w + o_inl);
  short* w2t   = (short*)(w + o_w2t);
  short* gw1t  = (short*)(w + o_gw1t);
  short* gw2t  = (short*)(w + o_gw2t);
  short* ow1t  = (short*)(w + o_ow1t);
  short* ow2t  = (short*)(w + o_ow2t);

  hipMemsetAsync(cnt, 0, (size_t)N*4, stream);
  hipMemsetAsync(out, 0, (size_t)G*4, stream);

  {
    int n8 = H*H/8;
    k_cvtT<<<(n8+255)/256, 256, 0, stream>>>(inW2, w2t, H, H);
    for (int c=0;c<4;c++){
      k_cvtT<<<(n8+255)/256, 256, 0, stream>>>(gW1 + (size_t)c*H*H, gw1t + (size_t)c*H*H, H, H);
      k_cvtT<<<(n8+255)/256, 256, 0, stream>>>(gW2 + (size_t)c*H*H, gw2t + (size_t)c*H*H, H, H);
    }
    int n1 = H*2*H/8;
    k_cvtT<<<(n1+255)/256, 256, 0, stream>>>(oW1, ow1t, 2*H, H);
    int n2 = (H/2)*H/8;
    k_cvtT<<<(n2+255)/256, 256, 0, stream>>>(oW2, ow2t, H, H/2);
  }

  k_pre<<<(E+255)/256, 256, 0, stream>>>(ei, n2g, nl, sig, pos, dnoi, E, pd, cnt, inl);
  k_ninit<<<(N*64+255)/256, 256, 0, stream>>>(at, nemb, xA, N);
  k_attr<<<(E+63)/64, 256, 0, stream>>>(pd, inW1, inb1, w2t, inb2, etype, eemb, attrS, E);

  // ping-pong: A->B->A->B->A ; head reads xA
  float* bufs[2] = {xA, xB};
  for (int c=0; c<4; c++){
    float* xin  = bufs[c & 1];
    float* xout = bufs[(c & 1) ^ 1];
    k_mlp<<<(N+31)/32, 256, 0, stream>>>(xin, (const uint2*)attrS, ei, cnt, inl,
        gw1t + (size_t)c*H*H, gb1 + (size_t)c*H,
        gw2t + (size_t)c*H*H, gb2 + (size_t)c*H,
        xout, N, (c<3) ? 1 : 0);
  }

  k_head<<<(E+63)/64, 256, 0, stream>>>(xA, attrS, ei, n2g,
      ow1t, ob1, ow2t, ob2, oW3, ob3, dnoi, out, E);
}

// Round 4
// 744.884 us; speedup vs baseline: 3.2155x; 1.2328x over previous
//
#include <hip/hip_runtime.h>
#include <math.h>

typedef unsigned int u32;
typedef __attribute__((ext_vector_type(8))) short bf16x8;
typedef __attribute__((ext_vector_type(4))) float f32x4;

#define MFMA16(a,b,c) __builtin_amdgcn_mfma_f32_16x16x32_bf16(a,b,c,0,0,0)

// ---------- bf16 helpers ----------
__device__ inline u32 bf16r(float x){
  u32 u = __float_as_uint(x);
  return (u + 0x7fffu + ((u >> 16) & 1u)) >> 16;
}
__device__ inline u32 pack2(float a, float b){ return bf16r(a) | (bf16r(b) << 16); }
__device__ inline uint4 pack8(const float* f){
  uint4 v; v.x = pack2(f[0],f[1]); v.y = pack2(f[2],f[3]);
  v.z = pack2(f[4],f[5]); v.w = pack2(f[6],f[7]); return v;
}
__device__ inline float bf2f(short s){ return __uint_as_float(((u32)(unsigned short)s) << 16); }

// async global->LDS, 16B per lane; lds dest must be wave-uniform base (HW adds lane*16)
__device__ __forceinline__ void gload_lds16(const void* g, void* l){
  __builtin_amdgcn_global_load_lds((const __attribute__((address_space(1))) unsigned int*)g,
                                   (__attribute__((address_space(3))) unsigned int*)l,
                                   16, 0, 0);
}

// ---------- weight convert: f32 [K][Nf] -> bf16 K-sliced tiles [K/32][Nf][32] with chunk swizzle ----------
// within a slice, row f holds k-chunk c (8 shorts) at position c ^ ((f>>1)&3)
__global__ void k_cvtT2(const float* __restrict__ in, short* __restrict__ out, int K, int Nf){
  int t = blockIdx.x*256 + threadIdx.x;
  int S = K >> 5;
  if (t >= S*Nf*4) return;
  int s = t / (Nf*4);
  int r = t - s*(Nf*4);
  int f = r >> 2, c = r & 3;
  float v[8];
  #pragma unroll
  for (int j=0;j<8;j++) v[j] = in[(size_t)(s*32 + c*8 + j)*Nf + f];
  int cs = c ^ ((f>>1)&3);
  ((uint4*)out)[((size_t)s*Nf*32 + (size_t)f*32 + cs*8) >> 3] = pack8(v);
}

// ---------- per-edge scalars + CSR in-edge lists ----------
__global__ void k_pre(const int* __restrict__ ei, const int* __restrict__ n2g,
                      const int* __restrict__ nl, const float* __restrict__ sigmas,
                      const float* __restrict__ pos, const float* __restrict__ dn, int E,
                      float* __restrict__ pd, int* __restrict__ cnt, int* __restrict__ inlist){
  int e = blockIdx.x*256 + threadIdx.x;
  if (e >= E) return;
  int r = ei[e], c = ei[E+e];
  float sg = sigmas[nl[n2g[r]]];
  float dx = pos[3*r]-pos[3*c], dy = pos[3*r+1]-pos[3*c+1], dz = pos[3*r+2]-pos[3*c+2];
  float d = sqrtf(dx*dx + dy*dy + dz*dz);
  pd[e] = d + dn[e]*sg;
  int slot = atomicAdd(&cnt[c], 1);
  if (slot < 8) inlist[c*8 + slot] = e;
}

// ---------- x = node_emb[atom_type] ----------
__global__ void k_ninit(const int* __restrict__ at, const float* __restrict__ nemb,
                        float* __restrict__ x, int N){
  int idx = blockIdx.x*256 + threadIdx.x;
  int i = idx >> 6, c = idx & 63;
  if (i >= N) return;
  ((float4*)x)[(size_t)i*64 + c] = ((const float4*)nemb)[(size_t)at[i]*64 + c];
}

// ---------- edge_attr: 64 edges/block; hidden [64][256]sw in LDS; W2 slices via global_load_lds ----------
__global__ __launch_bounds__(256,3) void k_attr(
    const float* __restrict__ pd, const float* __restrict__ W1, const float* __restrict__ b1,
    const short* __restrict__ W2t, const float* __restrict__ b2,
    const int* __restrict__ etype, const float* __restrict__ eemb,
    short* __restrict__ attr, int E)
{
  __shared__ short Als[64*256];   // 32 KB, chunk-swizzled
  __shared__ short Wls[256*32];   // 16 KB slice buffer
  int tid = threadIdx.x;
  int base = blockIdx.x*64;
  for (int q=0;q<8;q++){
    int lin = q*256 + tid;
    int el = lin >> 5, c8 = lin & 31, h8 = c8*8;
    int e = base + el;
    float f[8];
    if (e < E){
      float p = pd[e];
      float4 wa = *(const float4*)(W1+h8), wb = *(const float4*)(W1+h8+4);
      float4 ba = *(const float4*)(b1+h8), bb = *(const float4*)(b1+h8+4);
      f[0]=fmaxf(p*wa.x+ba.x,0.f); f[1]=fmaxf(p*wa.y+ba.y,0.f);
      f[2]=fmaxf(p*wa.z+ba.z,0.f); f[3]=fmaxf(p*wa.w+ba.w,0.f);
      f[4]=fmaxf(p*wb.x+bb.x,0.f); f[5]=fmaxf(p*wb.y+bb.y,0.f);
      f[6]=fmaxf(p*wb.z+bb.z,0.f); f[7]=fmaxf(p*wb.w+bb.w,0.f);
    } else { for (int t2=0;t2<8;t2++) f[t2]=0.f; }
    *(uint4*)(Als + el*256 + ((c8 ^ (el&7))*8)) = pack8(f);
  }
  int wv = tid>>6, lane = tid&63, quad = lane>>4, l15 = lane&15;
  f32x4 acc[4][4];
  #pragma unroll
  for (int mt=0;mt<4;mt++) for (int nt=0;nt<4;nt++) acc[mt][nt] = (f32x4)0.f;
  for (int s=0; s<8; s++){
    {
      const char* gs = (const char*)(W2t + (size_t)s*8192) + wv*4096 + lane*16;
      char* ld = (char*)Wls + wv*4096;
      #pragma unroll
      for (int i=0;i<4;i++) gload_lds16(gs + i*1024, ld + i*1024);
    }
    __syncthreads();
    bf16x8 a[4], b[4];
    #pragma unroll
    for (int mt=0;mt<4;mt++){
      int f = (wv*4+mt)*16 + l15;
      a[mt] = *(const bf16x8*)(Wls + f*32 + ((quad ^ ((f>>1)&3))*8));
    }
    #pragma unroll
    for (int nt=0;nt<4;nt++){
      int n = nt*16 + l15; int cc = s*4 + quad;
      b[nt] = *(const bf16x8*)(Als + n*256 + ((cc ^ (n&7))*8));
    }
    #pragma unroll
    for (int mt=0;mt<4;mt++)
      #pragma unroll
      for (int nt=0;nt<4;nt++)
        acc[mt][nt] = MFMA16(a[mt], b[nt], acc[mt][nt]);
    __syncthreads();
  }
  #pragma unroll
  for (int nt=0;nt<4;nt++){
    int e = base + nt*16 + l15;
    if (e < E){
      int et = etype[e];
      #pragma unroll
      for (int mt=0;mt<4;mt++){
        int f0 = (wv*4+mt)*16 + quad*4;
        float4 bb = *(const float4*)(b2 + f0);
        float4 em = *(const float4*)(eemb + (size_t)et*256 + f0);
        float v0 = (acc[mt][nt][0]+bb.x)*em.x, v1 = (acc[mt][nt][1]+bb.y)*em.y;
        float v2 = (acc[mt][nt][2]+bb.z)*em.z, v3 = (acc[mt][nt][3]+bb.w)*em.w;
        uint2 v; v.x = pack2(v0,v1); v.y = pack2(v2,v3);
        *(uint2*)(attr + (size_t)e*256 + f0) = v;
      }
    }
  }
}

// ---------- fused GIN conv: gather-staging + 2 GEMMs; 64 nodes/block ----------
__global__ __launch_bounds__(256,3) void k_mlp(
    const float* __restrict__ x_in, const uint2* __restrict__ attr2,
    const int* __restrict__ ei, const int* __restrict__ cnt, const int* __restrict__ inlist,
    const short* __restrict__ W1t, const float* __restrict__ b1,
    const short* __restrict__ W2t, const float* __restrict__ b2,
    float* __restrict__ x_out, int N, int do_relu)
{
  __shared__ short Als[64*256];   // 32 KB; T1 aliases after GEMM1
  __shared__ short Wls[256*32];   // 16 KB
  short* T1 = Als;
  int tid = threadIdx.x;
  int base = blockIdx.x*64;
  // gather staging: hin[j] = x[j] + sum relu(x[row]+attr); 8 thr/node x 32 feats, two halves
  for (int h=0; h<2; h++){
    int el = h*32 + (tid>>3), ch = tid&7;
    int j = base + el;
    if (j < N){
      float f[32];
      const float4* xj = (const float4*)x_in + (size_t)j*64 + ch*8;
      #pragma unroll
      for (int i=0;i<8;i++){ float4 v = xj[i]; f[i*4]=v.x; f[i*4+1]=v.y; f[i*4+2]=v.z; f[i*4+3]=v.w; }
      int deg = min(cnt[j], 8);
      for (int sIt=0; sIt<deg; sIt++){
        int e = inlist[j*8 + sIt];
        int r = ei[e];
        const float4* xr = (const float4*)x_in + (size_t)r*64 + ch*8;
        const uint2* av = attr2 + (size_t)e*64 + ch*8;
        #pragma unroll
        for (int i=0;i<8;i++){
          float4 xv = xr[i]; uint2 a = av[i];
          f[i*4]   += fmaxf(xv.x + __uint_as_float(a.x<<16), 0.f);
          f[i*4+1] += fmaxf(xv.y + __uint_as_float(a.x&0xffff0000u), 0.f);
          f[i*4+2] += fmaxf(xv.z + __uint_as_float(a.y<<16), 0.f);
          f[i*4+3] += fmaxf(xv.w + __uint_as_float(a.y&0xffff0000u), 0.f);
        }
      }
      #pragma unroll
      for (int qq=0;qq<4;qq++)
        *(uint4*)(Als + el*256 + (((ch*4+qq) ^ (el&7))*8)) = pack8(f + qq*8);
    }
  }
  int wv = tid>>6, lane = tid&63, quad = lane>>4, l15 = lane&15;
  // ---- GEMM1 ----
  f32x4 acc[4][4];
  #pragma unroll
  for (int mt=0;mt<4;mt++) for (int nt=0;nt<4;nt++) acc[mt][nt] = (f32x4)0.f;
  for (int s=0; s<8; s++){
    {
      const char* gs = (const char*)(W1t + (size_t)s*8192) + wv*4096 + lane*16;
      char* ld = (char*)Wls + wv*4096;
      #pragma unroll
      for (int i=0;i<4;i++) gload_lds16(gs + i*1024, ld + i*1024);
    }
    __syncthreads();
    bf16x8 a[4], b[4];
    #pragma unroll
    for (int mt=0;mt<4;mt++){
      int f = (wv*4+mt)*16 + l15;
      a[mt] = *(const bf16x8*)(Wls + f*32 + ((quad ^ ((f>>1)&3))*8));
    }
    #pragma unroll
    for (int nt=0;nt<4;nt++){
      int n = nt*16 + l15; int cc = s*4 + quad;
      b[nt] = *(const bf16x8*)(Als + n*256 + ((cc ^ (n&7))*8));
    }
    #pragma unroll
    for (int mt=0;mt<4;mt++)
      #pragma unroll
      for (int nt=0;nt<4;nt++)
        acc[mt][nt] = MFMA16(a[mt], b[nt], acc[mt][nt]);
    __syncthreads();
  }
  // write T1 (aliases Als; all reads done after trailing barrier)
  #pragma unroll
  for (int mt=0;mt<4;mt++){
    int f0 = (wv*4+mt)*16 + quad*4;
    float4 bb = *(const float4*)(b1 + f0);
    int c = f0 >> 3, off = (quad&1)*4;
    #pragma unroll
    for (int nt=0;nt<4;nt++){
      int n = nt*16 + l15;
      float v0 = fmaxf(acc[mt][nt][0]+bb.x,0.f), v1 = fmaxf(acc[mt][nt][1]+bb.y,0.f);
      float v2 = fmaxf(acc[mt][nt][2]+bb.z,0.f), v3 = fmaxf(acc[mt][nt][3]+bb.w,0.f);
      uint2 v; v.x = pack2(v0,v1); v.y = pack2(v2,v3);
      *(uint2*)(T1 + n*256 + ((c ^ (n&7))*8) + off) = v;
    }
  }
  // ---- GEMM2 ----
  f32x4 acc2[4][4];
  #pragma unroll
  for (int mt=0;mt<4;mt++) for (int nt=0;nt<4;nt++) acc2[mt][nt] = (f32x4)0.f;
  for (int s=0; s<8; s++){
    {
      const char* gs = (const char*)(W2t + (size_t)s*8192) + wv*4096 + lane*16;
      char* ld = (char*)Wls + wv*4096;
      #pragma unroll
      for (int i=0;i<4;i++) gload_lds16(gs + i*1024, ld + i*1024);
    }
    __syncthreads();
    bf16x8 a[4], b[4];
    #pragma unroll
    for (int mt=0;mt<4;mt++){
      int f = (wv*4+mt)*16 + l15;
      a[mt] = *(const bf16x8*)(Wls + f*32 + ((quad ^ ((f>>1)&3))*8));
    }
    #pragma unroll
    for (int nt=0;nt<4;nt++){
      int n = nt*16 + l15; int cc = s*4 + quad;
      b[nt] = *(const bf16x8*)(T1 + n*256 + ((cc ^ (n&7))*8));
    }
    #pragma unroll
    for (int mt=0;mt<4;mt++)
      #pragma unroll
      for (int nt=0;nt<4;nt++)
        acc2[mt][nt] = MFMA16(a[mt], b[nt], acc2[mt][nt]);
    __syncthreads();
  }
  #pragma unroll
  for (int mt=0;mt<4;mt++){
    int f0 = (wv*4+mt)*16 + quad*4;
    float4 bb = *(const float4*)(b2 + f0);
    #pragma unroll
    for (int nt=0;nt<4;nt++){
      int r = base + nt*16 + l15;
      if (r < N){
        const float* pin = x_in + (size_t)r*256 + f0;
        float* pout = x_out + (size_t)r*256 + f0;
        float4 xv = *(const float4*)pin;
        float h0 = acc2[mt][nt][0]+bb.x, h1 = acc2[mt][nt][1]+bb.y;
        float h2 = acc2[mt][nt][2]+bb.z, h3 = acc2[mt][nt][3]+bb.w;
        if (do_relu){ h0=fmaxf(h0,0.f); h1=fmaxf(h1,0.f); h2=fmaxf(h2,0.f); h3=fmaxf(h3,0.f); }
        xv.x += h0; xv.y += h1; xv.z += h2; xv.w += h3;
        *(float4*)pout = xv;
      }
    }
  }
}

// ---------- fused head: 32 edges/block; F [32][512]sw; W slices via global_load_lds ----------
__global__ __launch_bounds__(256,3) void k_head(
    const float* __restrict__ x, const short* __restrict__ attrS,
    const int* __restrict__ ei, const int* __restrict__ n2g,
    const short* __restrict__ W1t, const float* __restrict__ ob1,
    const short* __restrict__ W2t, const float* __restrict__ ob2,
    const float* __restrict__ W3, const float* __restrict__ ob3,
    const float* __restrict__ dnoise, float* __restrict__ out, int E)
{
  __shared__ short F[32*512];     // 32 KB; T1 [32][256] @0, T2 [32][128] @ 32*256 after L1
  __shared__ short Wls[256*32];   // 16 KB
  __shared__ float W3s[128];
  short* T1 = F;
  short* T2 = F + 32*256;
  int tid = threadIdx.x;
  int base = blockIdx.x*32;
  for (int q=0;q<8;q++){
    int lin = q*256 + tid;
    int el = lin >> 6, c8 = lin & 63, h8 = c8*8;
    int e = base + el;
    uint4 v;
    if (e < E){
      if (h8 < 256){
        int r = ei[e], c = ei[E+e];
        const float4* xr = (const float4*)(x + (size_t)r*256 + h8);
        const float4* xc = (const float4*)(x + (size_t)c*256 + h8);
        float4 a0 = xr[0], a1 = xr[1], b0 = xc[0], b1 = xc[1];
        float f[8] = {a0.x*b0.x, a0.y*b0.y, a0.z*b0.z, a0.w*b0.w,
                      a1.x*b1.x, a1.y*b1.y, a1.z*b1.z, a1.w*b1.w};
        v = pack8(f);
      } else {
        v = ((const uint4*)attrS)[((size_t)e*256 + (h8-256)) >> 3];
      }
    } else v = make_uint4(0,0,0,0);
    *(uint4*)(F + el*512 + ((c8 ^ (el&7))*8)) = v;
  }
  if (tid < 128) W3s[tid] = W3[tid];
  int wv = tid>>6, lane = tid&63, quad = lane>>4, l15 = lane&15;
  // ---- L1: K=512 (16 slices), M=256, N=32 ----
  f32x4 acc[4][2];
  #pragma unroll
  for (int mt=0;mt<4;mt++) for (int nt=0;nt<2;nt++) acc[mt][nt] = (f32x4)0.f;
  for (int s=0; s<16; s++){
    {
      const char* gs = (const char*)(W1t + (size_t)s*8192) + wv*4096 + lane*16;
      char* ld = (char*)Wls + wv*4096;
      #pragma unroll
      for (int i=0;i<4;i++) gload_lds16(gs + i*1024, ld + i*1024);
    }
    __syncthreads();
    bf16x8 a[4], b[2];
    #pragma unroll
    for (int mt=0;mt<4;mt++){
      int f = (wv*4+mt)*16 + l15;
      a[mt] = *(const bf16x8*)(Wls + f*32 + ((quad ^ ((f>>1)&3))*8));
    }
    #pragma unroll
    for (int nt=0;nt<2;nt++){
      int n = nt*16 + l15; int cc = s*4 + quad;
      b[nt] = *(const bf16x8*)(F + n*512 + ((cc ^ (n&7))*8));
    }
    #pragma unroll
    for (int mt=0;mt<4;mt++)
      #pragma unroll
      for (int nt=0;nt<2;nt++)
        acc[mt][nt] = MFMA16(a[mt], b[nt], acc[mt][nt]);
    __syncthreads();
  }
  // write T1 (aliases F region; F reads complete after trailing barrier)
  #pragma unroll
  for (int mt=0;mt<4;mt++){
    int f0 = (wv*4+mt)*16 + quad*4;
    float4 bb = *(const float4*)(ob1 + f0);
    int c = f0 >> 3, off = (quad&1)*4;
    #pragma unroll
    for (int nt=0;nt<2;nt++){
      int n = nt*16 + l15;
      float v0 = fmaxf(acc[mt][nt][0]+bb.x,0.f), v1 = fmaxf(acc[mt][nt][1]+bb.y,0.f);
      float v2 = fmaxf(acc[mt][nt][2]+bb.z,0.f), v3 = fmaxf(acc[mt][nt][3]+bb.w,0.f);
      uint2 v; v.x = pack2(v0,v1); v.y = pack2(v2,v3);
      *(uint2*)(T1 + n*256 + ((c ^ (n&7))*8) + off) = v;
    }
  }
  // ---- L2: K=256 (8 slices), M=128, N=32 ----
  f32x4 acc2[2][2];
  #pragma unroll
  for (int mt=0;mt<2;mt++) for (int nt=0;nt<2;nt++) acc2[mt][nt] = (f32x4)0.f;
  for (int s=0; s<8; s++){
    {
      const char* gs = (const char*)(W2t + (size_t)s*4096) + wv*2048 + lane*16;
      char* ld = (char*)Wls + wv*2048;
      #pragma unroll
      for (int i=0;i<2;i++) gload_lds16(gs + i*1024, ld + i*1024);
    }
    __syncthreads();
    bf16x8 a[2], b[2];
    #pragma unroll
    for (int mt=0;mt<2;mt++){
      int f = (wv*2+mt)*16 + l15;
      a[mt] = *(const bf16x8*)(Wls + f*32 + ((quad ^ ((f>>1)&3))*8));
    }
    #pragma unroll
    for (int nt=0;nt<2;nt++){
      int n = nt*16 + l15; int cc = s*4 + quad;
      b[nt] = *(const bf16x8*)(T1 + n*256 + ((cc ^ (n&7))*8));
    }
    #pragma unroll
    for (int mt=0;mt<2;mt++)
      #pragma unroll
      for (int nt=0;nt<2;nt++)
        acc2[mt][nt] = MFMA16(a[mt], b[nt], acc2[mt][nt]);
    __syncthreads();
  }
  #pragma unroll
  for (int mt=0;mt<2;mt++){
    int f0 = (wv*2+mt)*16 + quad*4;
    float4 bb = *(const float4*)(ob2 + f0);
    int c = f0 >> 3, off = (quad&1)*4;
    #pragma unroll
    for (int nt=0;nt<2;nt++){
      int n = nt*16 + l15;
      float v0 = fmaxf(acc2[mt][nt][0]+bb.x,0.f), v1 = fmaxf(acc2[mt][nt][1]+bb.y,0.f);
      float v2 = fmaxf(acc2[mt][nt][2]+bb.z,0.f), v3 = fmaxf(acc2[mt][nt][3]+bb.w,0.f);
      uint2 v; v.x = pack2(v0,v1); v.y = pack2(v2,v3);
      *(uint2*)(T2 + n*128 + ((c ^ (n&7))*8) + off) = v;
    }
  }
  __syncthreads();
  // ---- L3: K=128 + loss; 8 thr/edge ----
  int el = tid >> 3, part = tid & 7;
  float s = 0.f;
  #pragma unroll
  for (int t2=0;t2<2;t2++){
    int cc = part*2 + t2;
    bf16x8 v = *(const bf16x8*)(T2 + el*128 + ((cc ^ (el&7))*8));
    #pragma unroll
    for (int c=0;c<8;c++) s += bf2f(v[c])*W3s[cc*8+c];
  }
  s += __shfl_xor(s, 1);
  s += __shfl_xor(s, 2);
  s += __shfl_xor(s, 4);
  if (part == 0){
    int e = base + el;
    if (e < E){
      float sv = s + ob3[0];
      float dn = dnoise[e];
      float l = 0.5f*(sv + dn)*(sv + dn);
      atomicAdd(&out[n2g[ei[e]]], l);
    }
  }
}

// =========================== host ===========================
static inline size_t alignup(size_t v){ return (v + 255) & ~(size_t)255; }

extern "C" void kernel_launch(void* const* d_in, const int* in_sizes, int n_in,
                              void* d_out, int out_size, void* d_ws, size_t ws_size,
                              hipStream_t stream) {
  const int*   at    = (const int*)  d_in[0];
  const int*   ei    = (const int*)  d_in[1];
  const int*   etype = (const int*)  d_in[2];
  const int*   n2g   = (const int*)  d_in[3];
  const int*   nl    = (const int*)  d_in[4];
  const float* pos   = (const float*)d_in[5];
  const float* dnoi  = (const float*)d_in[6];
  const float* sig   = (const float*)d_in[7];
  const float* nemb  = (const float*)d_in[8];
  const float* eemb  = (const float*)d_in[9];
  const float* inW1  = (const float*)d_in[10];
  const float* inb1  = (const float*)d_in[11];
  const float* inW2  = (const float*)d_in[12];
  const float* inb2  = (const float*)d_in[13];
  const float* gW1   = (const float*)d_in[14];
  const float* gb1   = (const float*)d_in[15];
  const float* gW2   = (const float*)d_in[16];
  const float* gb2   = (const float*)d_in[17];
  const float* oW1   = (const float*)d_in[18];
  const float* ob1   = (const float*)d_in[19];
  const float* oW2   = (const float*)d_in[20];
  const float* ob2   = (const float*)d_in[21];
  const float* oW3   = (const float*)d_in[22];
  const float* ob3   = (const float*)d_in[23];
  float* out = (float*)d_out;

  const int N = in_sizes[0];
  const int E = in_sizes[2];
  const int G = in_sizes[4];
  const int H = 256;

  char* w = (char*)d_ws;
  size_t off = 0;
  size_t o_attr  = off; off = alignup(off + (size_t)E*H*2);
  size_t o_xA    = off; off = alignup(off + (size_t)N*H*4);
  size_t o_xB    = off; off = alignup(off + (size_t)N*H*4);
  size_t o_pd    = off; off = alignup(off + (size_t)E*4);
  size_t o_cnt   = off; off = alignup(off + (size_t)N*4);
  size_t o_inl   = off; off = alignup(off + (size_t)N*8*4);
  size_t o_w2t   = off; off = alignup(off + (size_t)H*H*2);
  size_t o_gw1t  = off; off = alignup(off + (size_t)4*H*H*2);
  size_t o_gw2t  = off; off = alignup(off + (size_t)4*H*H*2);
  size_t o_ow1t  = off; off = alignup(off + (size_t)H*2*H*2);
  size_t o_ow2t  = off; off = alignup(off + (size_t)(H/2)*H*2);
  (void)ws_size; (void)n_in; (void)out_size;

  short* attrS = (short*)(w + o_attr);
  float* xA    = (float*)(w + o_xA);
  float* xB    = (float*)(w + o_xB);
  float* pd    = (float*)(w + o_pd);
  int*   cnt   = (int*)  (w + o_cnt);
  int*   inl   = (int*)  (w + o_inl);
  short* w2t   = (short*)(w + o_w2t);
  short* gw1t  = (short*)(w + o_gw1t);
  short* gw2t  = (short*)(w + o_gw2t);
  short* ow1t  = (short*)(w + o_ow1t);
  short* ow2t  = (short*)(w + o_ow2t);

  hipMemsetAsync(cnt, 0, (size_t)N*4, stream);
  hipMemsetAsync(out, 0, (size_t)G*4, stream);

  // tiled+swizzled bf16 weight conversions
  {
    int n1 = (H/32)*H*4;     // 256x256: 8 slices
    k_cvtT2<<<(n1+255)/256, 256, 0, stream>>>(inW2, w2t, H, H);
    for (int c=0;c<4;c++){
      k_cvtT2<<<(n1+255)/256, 256, 0, stream>>>(gW1 + (size_t)c*H*H, gw1t + (size_t)c*H*H, H, H);
      k_cvtT2<<<(n1+255)/256, 256, 0, stream>>>(gW2 + (size_t)c*H*H, gw2t + (size_t)c*H*H, H, H);
    }
    int n2 = (2*H/32)*H*4;   // 512x256: 16 slices
    k_cvtT2<<<(n2+255)/256, 256, 0, stream>>>(oW1, ow1t, 2*H, H);
    int n3 = (H/32)*(H/2)*4; // 256x128: 8 slices
    k_cvtT2<<<(n3+255)/256, 256, 0, stream>>>(oW2, ow2t, H, H/2);
  }

  k_pre<<<(E+255)/256, 256, 0, stream>>>(ei, n2g, nl, sig, pos, dnoi, E, pd, cnt, inl);
  k_ninit<<<(N*64+255)/256, 256, 0, stream>>>(at, nemb, xA, N);
  k_attr<<<(E+63)/64, 256, 0, stream>>>(pd, inW1, inb1, w2t, inb2, etype, eemb, attrS, E);

  float* bufs[2] = {xA, xB};
  for (int c=0; c<4; c++){
    float* xin  = bufs[c & 1];
    float* xout = bufs[(c & 1) ^ 1];
    k_mlp<<<(N+63)/64, 256, 0, stream>>>(xin, (const uint2*)attrS, ei, cnt, inl,
        gw1t + (size_t)c*H*H, gb1 + (size_t)c*H,
        gw2t + (size_t)c*H*H, gb2 + (size_t)c*H,
        xout, N, (c<3) ? 1 : 0);
  }

  k_head<<<(E+31)/32, 256, 0, stream>>>(xA, attrS, ei, n2g,
      ow1t, ob1, ow2t, ob2, oW3, ob3, dnoi, out, E);
}

// Round 5
// 653.867 us; speedup vs baseline: 3.6631x; 1.1392x over previous
//
#include <hip/hip_runtime.h>
#include <math.h>

typedef unsigned int u32;
typedef __attribute__((ext_vector_type(8))) short bf16x8;
typedef __attribute__((ext_vector_type(4))) float f32x4;

#define MFMA16(a,b,c) __builtin_amdgcn_mfma_f32_16x16x32_bf16(a,b,c,0,0,0)

// ---------- bf16 helpers ----------
__device__ inline u32 bf16r(float x){
  u32 u = __float_as_uint(x);
  return (u + 0x7fffu + ((u >> 16) & 1u)) >> 16;
}
__device__ inline u32 pack2(float a, float b){ return bf16r(a) | (bf16r(b) << 16); }
__device__ inline uint4 pack8(const float* f){
  uint4 v; v.x = pack2(f[0],f[1]); v.y = pack2(f[2],f[3]);
  v.z = pack2(f[4],f[5]); v.w = pack2(f[6],f[7]); return v;
}
__device__ inline float bf2f(short s){ return __uint_as_float(((u32)(unsigned short)s) << 16); }

// async global->LDS, 16B/lane; dest = wave-uniform base + lane*16 (src per-lane OK)
__device__ __forceinline__ void gload_lds16(const void* g, void* l){
  __builtin_amdgcn_global_load_lds((const __attribute__((address_space(1))) unsigned int*)g,
                                   (__attribute__((address_space(3))) unsigned int*)l,
                                   16, 0, 0);
}

// A/B fragment LDS offset (shorts) in the paired-macro-row swizzled tile layout.
// Tile = [Nf rows][32 k] stored as granules t: row f=(t>>3)*2+((t>>2)&1),
// chunk slot t&3 holds logical chunk ( (t&3) ^ ((t>>3)&3) ).
__device__ __forceinline__ int frag_off(int f, int quad){
  return (f>>1)*64 + (f&1)*32 + ((quad ^ ((f>>1)&3))*8);
}

// ---------- merged weight converter: f32 [K][Nf] -> sliced swizzled bf16 tiles ----------
__global__ void k_cvtAll(const float* __restrict__ inW2, const float* __restrict__ gW1,
                         const float* __restrict__ gW2, const float* __restrict__ oW1,
                         const float* __restrict__ oW2,
                         short* __restrict__ w2t, short* __restrict__ gw1t,
                         short* __restrict__ gw2t, short* __restrict__ ow1t,
                         short* __restrict__ ow2t){
  int gidx = blockIdx.x*256 + threadIdx.x;
  const float* src; short* dst; int Nf, t;
  if (gidx < 8192)      { src = inW2; dst = w2t; Nf = 256; t = gidx; }
  else if (gidx < 40960){ int r = gidx-8192;  int c = r>>13; t = r&8191;
                          src = gW1 + (size_t)c*65536; dst = gw1t + (size_t)c*65536; Nf = 256; }
  else if (gidx < 73728){ int r = gidx-40960; int c = r>>13; t = r&8191;
                          src = gW2 + (size_t)c*65536; dst = gw2t + (size_t)c*65536; Nf = 256; }
  else if (gidx < 90112){ t = gidx-73728; src = oW1; dst = ow1t; Nf = 256; }
  else if (gidx < 94208){ t = gidx-90112; src = oW2; dst = ow2t; Nf = 128; }
  else return;
  int perS = Nf*4;
  int s = t / perS, u = t - s*perS;
  int f = (u>>3)*2 + ((u>>2)&1);
  int c = (u&3) ^ ((u>>3)&3);
  float v[8];
  #pragma unroll
  for (int j=0;j<8;j++) v[j] = src[(size_t)(s*32 + c*8 + j)*Nf + f];
  ((uint4*)dst)[t] = pack8(v);
}

// ---------- per-edge scalars + CSR in-edge lists ----------
__global__ void k_pre(const int* __restrict__ ei, const int* __restrict__ n2g,
                      const int* __restrict__ nl, const float* __restrict__ sigmas,
                      const float* __restrict__ pos, const float* __restrict__ dn, int E,
                      float* __restrict__ pd, int* __restrict__ cnt, int* __restrict__ inlist){
  int e = blockIdx.x*256 + threadIdx.x;
  if (e >= E) return;
  int r = ei[e], c = ei[E+e];
  float sg = sigmas[nl[n2g[r]]];
  float dx = pos[3*r]-pos[3*c], dy = pos[3*r+1]-pos[3*c+1], dz = pos[3*r+2]-pos[3*c+2];
  float d = sqrtf(dx*dx + dy*dy + dz*dz);
  pd[e] = d + dn[e]*sg;
  int slot = atomicAdd(&cnt[c], 1);
  if (slot < 8) inlist[c*8 + slot] = e;
}

// ---------- x = node_emb[atom_type] ----------
__global__ void k_ninit(const int* __restrict__ at, const float* __restrict__ nemb,
                        float* __restrict__ x, int N){
  int idx = blockIdx.x*256 + threadIdx.x;
  int i = idx >> 6, c = idx & 63;
  if (i >= N) return;
  ((float4*)x)[(size_t)i*64 + c] = ((const float4*)nemb)[(size_t)at[i]*64 + c];
}

// ---------- edge_attr GEMM: M=256,K=256,N=128 edges/block; B computed per slice ----------
__global__ __launch_bounds__(256,2) void k_attr(
    const float* __restrict__ pd, const float* __restrict__ W1, const float* __restrict__ b1,
    const short* __restrict__ W2t, const float* __restrict__ b2,
    const int* __restrict__ etype, const float* __restrict__ eemb,
    short* __restrict__ attr, int E)
{
  __shared__ short Wls[256*32];   // 16 KB
  __shared__ short Bls[128*32];   // 8 KB
  __shared__ float w1s[256], b1s[256], pls[128];
  __shared__ int etls[128];
  int tid = threadIdx.x;
  int base = blockIdx.x*128;
  if (tid < 128){ pls[tid] = pd[base+tid]; etls[tid] = etype[base+tid]; }
  w1s[tid] = W1[tid]; b1s[tid] = b1[tid];
  __syncthreads();
  int wv = tid>>6, lane = tid&63, quad = lane>>4, l15 = lane&15;
  f32x4 acc[4][8];
  #pragma unroll
  for (int mt=0;mt<4;mt++) for (int nt=0;nt<8;nt++) acc[mt][nt] = (f32x4)0.f;
  for (int s=0; s<8; s++){
    { // W slice 16 KB via load_lds (contiguous)
      const char* gs = (const char*)W2t + (size_t)s*16384 + wv*4096 + lane*16;
      char* ld = (char*)Wls + wv*4096;
      #pragma unroll
      for (int i=0;i<4;i++) gload_lds16(gs + i*1024, ld + i*1024);
    }
    // B slice: hidden[e][k] = relu(pd*W1+b1), 2 granules/thread
    #pragma unroll
    for (int q=0;q<2;q++){
      int g = tid*2 + q;
      int p = g>>3, hi = (g>>2)&1, cs = g&3;
      int c = cs ^ (p&3), n = p*2 + hi, k = s*32 + c*8;
      float pv = pls[n];
      float f[8];
      #pragma unroll
      for (int j=0;j<8;j++) f[j] = fmaxf(pv*w1s[k+j] + b1s[k+j], 0.f);
      ((uint4*)Bls)[g] = pack8(f);
    }
    __syncthreads();
    bf16x8 a[4], b[8];
    #pragma unroll
    for (int mt=0;mt<4;mt++)
      a[mt] = *(const bf16x8*)(Wls + frag_off((wv*4+mt)*16 + l15, quad));
    #pragma unroll
    for (int nt=0;nt<8;nt++)
      b[nt] = *(const bf16x8*)(Bls + frag_off(nt*16 + l15, quad));
    #pragma unroll
    for (int mt=0;mt<4;mt++)
      #pragma unroll
      for (int nt=0;nt<8;nt++)
        acc[mt][nt] = MFMA16(a[mt], b[nt], acc[mt][nt]);
    __syncthreads();
  }
  #pragma unroll
  for (int nt=0;nt<8;nt++){
    int e = base + nt*16 + l15;
    int et = etls[nt*16 + l15];
    #pragma unroll
    for (int mt=0;mt<4;mt++){
      int f0 = (wv*4+mt)*16 + quad*4;
      float4 bb = *(const float4*)(b2 + f0);
      float4 em = *(const float4*)(eemb + (size_t)et*256 + f0);
      float v0 = (acc[mt][nt][0]+bb.x)*em.x, v1 = (acc[mt][nt][1]+bb.y)*em.y;
      float v2 = (acc[mt][nt][2]+bb.z)*em.z, v3 = (acc[mt][nt][3]+bb.w)*em.w;
      uint2 v; v.x = pack2(v0,v1); v.y = pack2(v2,v3);
      *(uint2*)(attr + (size_t)e*256 + f0) = v;
    }
  }
}

// ---------- fused GIN conv (round-4 structure; new weight layout) ----------
__global__ __launch_bounds__(256,3) void k_mlp(
    const float* __restrict__ x_in, const uint2* __restrict__ attr2,
    const int* __restrict__ ei, const int* __restrict__ cnt, const int* __restrict__ inlist,
    const short* __restrict__ W1t, const float* __restrict__ b1,
    const short* __restrict__ W2t, const float* __restrict__ b2,
    float* __restrict__ x_out, int N, int do_relu)
{
  __shared__ short Als[64*256];   // 32 KB; T1 aliases after GEMM1
  __shared__ short Wls[256*32];   // 16 KB
  short* T1 = Als;
  int tid = threadIdx.x;
  int base = blockIdx.x*64;
  for (int h=0; h<2; h++){
    int el = h*32 + (tid>>3), ch = tid&7;
    int j = base + el;
    if (j < N){
      float f[32];
      const float4* xj = (const float4*)x_in + (size_t)j*64 + ch*8;
      #pragma unroll
      for (int i=0;i<8;i++){ float4 v = xj[i]; f[i*4]=v.x; f[i*4+1]=v.y; f[i*4+2]=v.z; f[i*4+3]=v.w; }
      int deg = min(cnt[j], 8);
      for (int sIt=0; sIt<deg; sIt++){
        int e = inlist[j*8 + sIt];
        int r = ei[e];
        const float4* xr = (const float4*)x_in + (size_t)r*64 + ch*8;
        const uint2* av = attr2 + (size_t)e*64 + ch*8;
        #pragma unroll
        for (int i=0;i<8;i++){
          float4 xv = xr[i]; uint2 a = av[i];
          f[i*4]   += fmaxf(xv.x + __uint_as_float(a.x<<16), 0.f);
          f[i*4+1] += fmaxf(xv.y + __uint_as_float(a.x&0xffff0000u), 0.f);
          f[i*4+2] += fmaxf(xv.z + __uint_as_float(a.y<<16), 0.f);
          f[i*4+3] += fmaxf(xv.w + __uint_as_float(a.y&0xffff0000u), 0.f);
        }
      }
      #pragma unroll
      for (int qq=0;qq<4;qq++)
        *(uint4*)(Als + el*256 + (((ch*4+qq) ^ (el&7))*8)) = pack8(f + qq*8);
    }
  }
  int wv = tid>>6, lane = tid&63, quad = lane>>4, l15 = lane&15;
  // ---- GEMM1 ----
  f32x4 acc[4][4];
  #pragma unroll
  for (int mt=0;mt<4;mt++) for (int nt=0;nt<4;nt++) acc[mt][nt] = (f32x4)0.f;
  for (int s=0; s<8; s++){
    {
      const char* gs = (const char*)W1t + (size_t)s*16384 + wv*4096 + lane*16;
      char* ld = (char*)Wls + wv*4096;
      #pragma unroll
      for (int i=0;i<4;i++) gload_lds16(gs + i*1024, ld + i*1024);
    }
    __syncthreads();
    bf16x8 a[4], b[4];
    #pragma unroll
    for (int mt=0;mt<4;mt++)
      a[mt] = *(const bf16x8*)(Wls + frag_off((wv*4+mt)*16 + l15, quad));
    #pragma unroll
    for (int nt=0;nt<4;nt++){
      int n = nt*16 + l15; int cc = s*4 + quad;
      b[nt] = *(const bf16x8*)(Als + n*256 + ((cc ^ (n&7))*8));
    }
    #pragma unroll
    for (int mt=0;mt<4;mt++)
      #pragma unroll
      for (int nt=0;nt<4;nt++)
        acc[mt][nt] = MFMA16(a[mt], b[nt], acc[mt][nt]);
    __syncthreads();
  }
  #pragma unroll
  for (int mt=0;mt<4;mt++){
    int f0 = (wv*4+mt)*16 + quad*4;
    float4 bb = *(const float4*)(b1 + f0);
    int c = f0 >> 3, off = (quad&1)*4;
    #pragma unroll
    for (int nt=0;nt<4;nt++){
      int n = nt*16 + l15;
      float v0 = fmaxf(acc[mt][nt][0]+bb.x,0.f), v1 = fmaxf(acc[mt][nt][1]+bb.y,0.f);
      float v2 = fmaxf(acc[mt][nt][2]+bb.z,0.f), v3 = fmaxf(acc[mt][nt][3]+bb.w,0.f);
      uint2 v; v.x = pack2(v0,v1); v.y = pack2(v2,v3);
      *(uint2*)(T1 + n*256 + ((c ^ (n&7))*8) + off) = v;
    }
  }
  // ---- GEMM2 ----
  f32x4 acc2[4][4];
  #pragma unroll
  for (int mt=0;mt<4;mt++) for (int nt=0;nt<4;nt++) acc2[mt][nt] = (f32x4)0.f;
  for (int s=0; s<8; s++){
    {
      const char* gs = (const char*)W2t + (size_t)s*16384 + wv*4096 + lane*16;
      char* ld = (char*)Wls + wv*4096;
      #pragma unroll
      for (int i=0;i<4;i++) gload_lds16(gs + i*1024, ld + i*1024);
    }
    __syncthreads();
    bf16x8 a[4], b[4];
    #pragma unroll
    for (int mt=0;mt<4;mt++)
      a[mt] = *(const bf16x8*)(Wls + frag_off((wv*4+mt)*16 + l15, quad));
    #pragma unroll
    for (int nt=0;nt<4;nt++){
      int n = nt*16 + l15; int cc = s*4 + quad;
      b[nt] = *(const bf16x8*)(T1 + n*256 + ((cc ^ (n&7))*8));
    }
    #pragma unroll
    for (int mt=0;mt<4;mt++)
      #pragma unroll
      for (int nt=0;nt<4;nt++)
        acc2[mt][nt] = MFMA16(a[mt], b[nt], acc2[mt][nt]);
    __syncthreads();
  }
  #pragma unroll
  for (int mt=0;mt<4;mt++){
    int f0 = (wv*4+mt)*16 + quad*4;
    float4 bb = *(const float4*)(b2 + f0);
    #pragma unroll
    for (int nt=0;nt<4;nt++){
      int r = base + nt*16 + l15;
      if (r < N){
        const float* pin = x_in + (size_t)r*256 + f0;
        float* pout = x_out + (size_t)r*256 + f0;
        float4 xv = *(const float4*)pin;
        float h0 = acc2[mt][nt][0]+bb.x, h1 = acc2[mt][nt][1]+bb.y;
        float h2 = acc2[mt][nt][2]+bb.z, h3 = acc2[mt][nt][3]+bb.w;
        if (do_relu){ h0=fmaxf(h0,0.f); h1=fmaxf(h1,0.f); h2=fmaxf(h2,0.f); h3=fmaxf(h3,0.f); }
        xv.x += h0; xv.y += h1; xv.z += h2; xv.w += h3;
        *(float4*)pout = xv;
      }
    }
  }
}

// ---------- head L1 GEMM: M=256,K=512,N=128/block; B = [x_r*x_c | attr] per slice ----------
__global__ __launch_bounds__(256,2) void k_headL1(
    const float* __restrict__ x, const short* __restrict__ attrS,
    const int* __restrict__ ei,
    const short* __restrict__ W1t, const float* __restrict__ ob1,
    short* __restrict__ H1, int E)
{
  __shared__ short Wls[256*32];   // 16 KB
  __shared__ short Bls[128*32];   // 8 KB
  __shared__ int rls[128], cls[128];
  int tid = threadIdx.x;
  int base = blockIdx.x*128;
  if (tid < 128){ rls[tid] = ei[base+tid]; cls[tid] = ei[E+base+tid]; }
  __syncthreads();
  int wv = tid>>6, lane = tid&63, quad = lane>>4, l15 = lane&15;
  f32x4 acc[4][8];
  #pragma unroll
  for (int mt=0;mt<4;mt++) for (int nt=0;nt<8;nt++) acc[mt][nt] = (f32x4)0.f;
  for (int s=0; s<16; s++){
    { // W slice 16 KB
      const char* gs = (const char*)W1t + (size_t)s*16384 + wv*4096 + lane*16;
      char* ld = (char*)Wls + wv*4096;
      #pragma unroll
      for (int i=0;i<4;i++) gload_lds16(gs + i*1024, ld + i*1024);
    }
    if (s < 8){
      // B = x_r * x_c for k-slice, VALU staged
      #pragma unroll
      for (int q=0;q<2;q++){
        int g = tid*2 + q;
        int p = g>>3, hi = (g>>2)&1, cs = g&3;
        int c = cs ^ (p&3), n = p*2 + hi, k = s*32 + c*8;
        const float4* xr = (const float4*)(x + (size_t)rls[n]*256 + k);
        const float4* xc = (const float4*)(x + (size_t)cls[n]*256 + k);
        float4 a0 = xr[0], a1 = xr[1], b0 = xc[0], b1 = xc[1];
        float f[8] = {a0.x*b0.x, a0.y*b0.y, a0.z*b0.z, a0.w*b0.w,
                      a1.x*b1.x, a1.y*b1.y, a1.z*b1.z, a1.w*b1.w};
        ((uint4*)Bls)[g] = pack8(f);
      }
    } else {
      // B = attr k-slice via load_lds (per-lane source)
      #pragma unroll
      for (int i=0;i<2;i++){
        int g = wv*128 + i*64 + lane;
        int p = g>>3, hi = (g>>2)&1, cs = g&3;
        int c = cs ^ (p&3), n = p*2 + hi;
        const short* src = attrS + (size_t)(base+n)*256 + (s-8)*32 + c*8;
        gload_lds16(src, (char*)Bls + (size_t)(wv*128 + i*64)*16);
      }
    }
    __syncthreads();
    bf16x8 a[4], b[8];
    #pragma unroll
    for (int mt=0;mt<4;mt++)
      a[mt] = *(const bf16x8*)(Wls + frag_off((wv*4+mt)*16 + l15, quad));
    #pragma unroll
    for (int nt=0;nt<8;nt++)
      b[nt] = *(const bf16x8*)(Bls + frag_off(nt*16 + l15, quad));
    #pragma unroll
    for (int mt=0;mt<4;mt++)
      #pragma unroll
      for (int nt=0;nt<8;nt++)
        acc[mt][nt] = MFMA16(a[mt], b[nt], acc[mt][nt]);
    __syncthreads();
  }
  #pragma unroll
  for (int mt=0;mt<4;mt++){
    int f0 = (wv*4+mt)*16 + quad*4;
    float4 bb = *(const float4*)(ob1 + f0);
    #pragma unroll
    for (int nt=0;nt<8;nt++){
      int e = base + nt*16 + l15;
      float v0 = fmaxf(acc[mt][nt][0]+bb.x,0.f), v1 = fmaxf(acc[mt][nt][1]+bb.y,0.f);
      float v2 = fmaxf(acc[mt][nt][2]+bb.z,0.f), v3 = fmaxf(acc[mt][nt][3]+bb.w,0.f);
      uint2 v; v.x = pack2(v0,v1); v.y = pack2(v2,v3);
      *(uint2*)(H1 + (size_t)e*256 + f0) = v;
    }
  }
}

// ---------- head L2 GEMM + L3 + loss: M=128,K=256,N=128/block ----------
__global__ __launch_bounds__(256,3) void k_headL2(
    const short* __restrict__ H1, const short* __restrict__ W2t,
    const float* __restrict__ ob2, const float* __restrict__ W3,
    const float* __restrict__ ob3, const float* __restrict__ dnoise,
    const int* __restrict__ ei, const int* __restrict__ n2g,
    float* __restrict__ out, int E)
{
  __shared__ short Wls[128*32];   // 8 KB
  __shared__ short Bls[128*32];   // 8 KB
  __shared__ float W3s[128];
  __shared__ float S[128];
  int tid = threadIdx.x;
  int base = blockIdx.x*128;
  if (tid < 128){ W3s[tid] = W3[tid]; S[tid] = 0.f; }
  __syncthreads();
  int wv = tid>>6, lane = tid&63, quad = lane>>4, l15 = lane&15;
  f32x4 acc[2][8];
  #pragma unroll
  for (int mt=0;mt<2;mt++) for (int nt=0;nt<8;nt++) acc[mt][nt] = (f32x4)0.f;
  for (int s=0; s<8; s++){
    { // W slice 8 KB
      const char* gs = (const char*)W2t + (size_t)s*8192 + wv*2048 + lane*16;
      char* ld = (char*)Wls + wv*2048;
      #pragma unroll
      for (int i=0;i<2;i++) gload_lds16(gs + i*1024, ld + i*1024);
    }
    { // B = H1 k-slice via load_lds
      #pragma unroll
      for (int i=0;i<2;i++){
        int g = wv*128 + i*64 + lane;
        int p = g>>3, hi = (g>>2)&1, cs = g&3;
        int c = cs ^ (p&3), n = p*2 + hi;
        const short* src = H1 + (size_t)(base+n)*256 + s*32 + c*8;
        gload_lds16(src, (char*)Bls + (size_t)(wv*128 + i*64)*16);
      }
    }
    __syncthreads();
    bf16x8 a[2], b[8];
    #pragma unroll
    for (int mt=0;mt<2;mt++)
      a[mt] = *(const bf16x8*)(Wls + frag_off((wv*2+mt)*16 + l15, quad));
    #pragma unroll
    for (int nt=0;nt<8;nt++)
      b[nt] = *(const bf16x8*)(Bls + frag_off(nt*16 + l15, quad));
    #pragma unroll
    for (int mt=0;mt<2;mt++)
      #pragma unroll
      for (int nt=0;nt<8;nt++)
        acc[mt][nt] = MFMA16(a[mt], b[nt], acc[mt][nt]);
    __syncthreads();
  }
  // L3 epilogue: per-lane partial dot with W3, LDS atomic reduce
  float4 b2v[2], w3v[2];
  #pragma unroll
  for (int mt=0;mt<2;mt++){
    int f0 = (wv*2+mt)*16 + quad*4;
    b2v[mt] = *(const float4*)(ob2 + f0);
    w3v[mt] = *(const float4*)(W3s + f0);
  }
  #pragma unroll
  for (int nt=0;nt<8;nt++){
    float p = 0.f;
    #pragma unroll
    for (int mt=0;mt<2;mt++){
      p += fmaxf(acc[mt][nt][0]+b2v[mt].x,0.f)*w3v[mt].x;
      p += fmaxf(acc[mt][nt][1]+b2v[mt].y,0.f)*w3v[mt].y;
      p += fmaxf(acc[mt][nt][2]+b2v[mt].z,0.f)*w3v[mt].z;
      p += fmaxf(acc[mt][nt][3]+b2v[mt].w,0.f)*w3v[mt].w;
    }
    atomicAdd(&S[nt*16 + l15], p);
  }
  __syncthreads();
  if (tid < 128){
    int e = base + tid;
    float sv = S[tid] + ob3[0];
    float dn = dnoise[e];
    float l = 0.5f*(sv + dn)*(sv + dn);
    atomicAdd(&out[n2g[ei[e]]], l);
  }
}

// =========================== host ===========================
static inline size_t alignup(size_t v){ return (v + 255) & ~(size_t)255; }

extern "C" void kernel_launch(void* const* d_in, const int* in_sizes, int n_in,
                              void* d_out, int out_size, void* d_ws, size_t ws_size,
                              hipStream_t stream) {
  const int*   at    = (const int*)  d_in[0];
  const int*   ei    = (const int*)  d_in[1];
  const int*   etype = (const int*)  d_in[2];
  const int*   n2g   = (const int*)  d_in[3];
  const int*   nl    = (const int*)  d_in[4];
  const float* pos   = (const float*)d_in[5];
  const float* dnoi  = (const float*)d_in[6];
  const float* sig   = (const float*)d_in[7];
  const float* nemb  = (const float*)d_in[8];
  const float* eemb  = (const float*)d_in[9];
  const float* inW1  = (const float*)d_in[10];
  const float* inb1  = (const float*)d_in[11];
  const float* inW2  = (const float*)d_in[12];
  const float* inb2  = (const float*)d_in[13];
  const float* gW1   = (const float*)d_in[14];
  const float* gb1   = (const float*)d_in[15];
  const float* gW2   = (const float*)d_in[16];
  const float* gb2   = (const float*)d_in[17];
  const float* oW1   = (const float*)d_in[18];
  const float* ob1   = (const float*)d_in[19];
  const float* oW2   = (const float*)d_in[20];
  const float* ob2   = (const float*)d_in[21];
  const float* oW3   = (const float*)d_in[22];
  const float* ob3   = (const float*)d_in[23];
  float* out = (float*)d_out;

  const int N = in_sizes[0];
  const int E = in_sizes[2];
  const int G = in_sizes[4];
  const int H = 256;

  char* w = (char*)d_ws;
  size_t off = 0;
  size_t o_attr  = off; off = alignup(off + (size_t)E*H*2);
  size_t o_h1    = off; off = alignup(off + (size_t)E*H*2);
  size_t o_xA    = off; off = alignup(off + (size_t)N*H*4);
  size_t o_xB    = off; off = alignup(off + (size_t)N*H*4);
  size_t o_pd    = off; off = alignup(off + (size_t)E*4);
  size_t o_cnt   = off; off = alignup(off + (size_t)N*4);
  size_t o_inl   = off; off = alignup(off + (size_t)N*8*4);
  size_t o_w2t   = off; off = alignup(off + (size_t)H*H*2);
  size_t o_gw1t  = off; off = alignup(off + (size_t)4*H*H*2);
  size_t o_gw2t  = off; off = alignup(off + (size_t)4*H*H*2);
  size_t o_ow1t  = off; off = alignup(off + (size_t)H*2*H*2);
  size_t o_ow2t  = off; off = alignup(off + (size_t)(H/2)*H*2);
  (void)ws_size; (void)n_in; (void)out_size;

  short* attrS = (short*)(w + o_attr);
  short* H1    = (short*)(w + o_h1);
  float* xA    = (float*)(w + o_xA);
  float* xB    = (float*)(w + o_xB);
  float* pd    = (float*)(w + o_pd);
  int*   cnt   = (int*)  (w + o_cnt);
  int*   inl   = (int*)  (w + o_inl);
  short* w2t   = (short*)(w + o_w2t);
  short* gw1t  = (short*)(w + o_gw1t);
  short* gw2t  = (short*)(w + o_gw2t);
  short* ow1t  = (short*)(w + o_ow1t);
  short* ow2t  = (short*)(w + o_ow2t);

  hipMemsetAsync(cnt, 0, (size_t)N*4, stream);
  hipMemsetAsync(out, 0, (size_t)G*4, stream);

  k_cvtAll<<<368, 256, 0, stream>>>(inW2, gW1, gW2, oW1, oW2,
                                    w2t, gw1t, gw2t, ow1t, ow2t);

  k_pre<<<(E+255)/256, 256, 0, stream>>>(ei, n2g, nl, sig, pos, dnoi, E, pd, cnt, inl);
  k_ninit<<<(N*64+255)/256, 256, 0, stream>>>(at, nemb, xA, N);
  k_attr<<<E/128, 256, 0, stream>>>(pd, inW1, inb1, w2t, inb2, etype, eemb, attrS, E);

  float* bufs[2] = {xA, xB};
  for (int c=0; c<4; c++){
    float* xin  = bufs[c & 1];
    float* xout = bufs[(c & 1) ^ 1];
    k_mlp<<<(N+63)/64, 256, 0, stream>>>(xin, (const uint2*)attrS, ei, cnt, inl,
        gw1t + (size_t)c*H*H, gb1 + (size_t)c*H,
        gw2t + (size_t)c*H*H, gb2 + (size_t)c*H,
        xout, N, (c<3) ? 1 : 0);
  }

  k_headL1<<<E/128, 256, 0, stream>>>(xA, attrS, ei, ow1t, ob1, H1, E);
  k_headL2<<<E/128, 256, 0, stream>>>(H1, ow2t, ob2, oW3, ob3, dnoi, ei, n2g, out, E);
}